// Round 1
// baseline (183.582 us; speedup 1.0000x reference)
//
#include <hip/hip_runtime.h>

// Problem constants
#define CC 8
#define NN 1024
#define TT 8
#define II 64
#define HH 4
#define FF 64
#define EE (CC*NN*16)          // 131072 edges
#define KK 256                 // F*H

// d_out layout: out (C,N,T,F) = 4,194,304 floats, then attn (C,N,N,H) = 33,554,432 floats
static const size_t OUT_ELEMS  = (size_t)CC*NN*TT*FF;
static const size_t ATTN_ELEMS = (size_t)CC*NN*NN*HH;

// ws layout (bytes)
//  P       : [C][T][N][256] f32  -> 67,108,864 B
//  a_src   : [C][N][H] f32       ->    131,072 B
//  a_dst   : [C][N][H] f32       ->    131,072 B
//  adj     : [C][N_dst][32] u32  ->  1,048,576 B  (bitset over src i)
static const size_t P_BYTES    = (size_t)CC*TT*NN*KK*4;
static const size_t ASRC_OFF   = P_BYTES;
static const size_t ADST_OFF   = ASRC_OFF + (size_t)CC*NN*HH*4;
static const size_t ADJ_OFF    = ADST_OFF + (size_t)CC*NN*HH*4;

// ---------------------------------------------------------------------------
// K1: projection P[c][t][n][k] = sum_i nf[c,n,t,i] * fc[t,i,k]
// grid = C*T*16 blocks (64-row tiles), 256 threads
// ---------------------------------------------------------------------------
__global__ __launch_bounds__(256) void k_proj(const float* __restrict__ nf,
                                              const float* __restrict__ fc,
                                              float* __restrict__ P) {
    __shared__ float fcs[64*128];   // 32 KB (half of fc[t] columns)
    __shared__ float nfs[64*64];    // 16 KB (64 node rows)
    int bx = blockIdx.x;
    int rowtile = bx & 15;
    int ct = bx >> 4;
    int c = ct >> 3, t = ct & 7;
    int n0 = rowtile * 64;
    int tid = threadIdx.x;

    for (int l = tid; l < 64*64; l += 256) {
        int r = l >> 6, i = l & 63;
        nfs[l] = nf[((size_t)(c*NN + n0 + r)*TT + t)*II + i];
    }
    int ci = tid & 31;     // column thread (cols ci, ci+32, ci+64, ci+96 within half)
    int rt = tid >> 5;     // row group 0..7 (rows rt*8 .. rt*8+7)

    for (int half = 0; half < 2; ++half) {
        __syncthreads();
        for (int l = tid; l < 64*128; l += 256) {
            int i = l >> 7, kk = l & 127;
            fcs[l] = fc[(size_t)(t*64 + i)*KK + half*128 + kk];
        }
        __syncthreads();
        float acc[8][4];
        #pragma unroll
        for (int v = 0; v < 8; ++v)
            #pragma unroll
            for (int u = 0; u < 4; ++u) acc[v][u] = 0.f;

        for (int i = 0; i < 64; ++i) {
            float b0 = fcs[i*128 + ci];
            float b1 = fcs[i*128 + ci + 32];
            float b2 = fcs[i*128 + ci + 64];
            float b3 = fcs[i*128 + ci + 96];
            #pragma unroll
            for (int v = 0; v < 8; ++v) {
                float av = nfs[(rt*8 + v)*64 + i];
                acc[v][0] += av*b0; acc[v][1] += av*b1;
                acc[v][2] += av*b2; acc[v][3] += av*b3;
            }
        }
        #pragma unroll
        for (int v = 0; v < 8; ++v) {
            int row = rt*8 + v;
            size_t base = ((size_t)(c*TT + t)*NN + n0 + row)*KK + half*128 + ci;
            P[base]      = acc[v][0];
            P[base + 32] = acc[v][1];
            P[base + 64] = acc[v][2];
            P[base + 96] = acc[v][3];
        }
    }
}

// ---------------------------------------------------------------------------
// K2: attention logits a_src/a_dst [c][n][h] = sum_{t2,f2} feat3 * attn_vec
// feat3[c,n,h,t2,f2] = P[c][n>>7][(n&127)*8+t2][h*64+f2]
// one wave per (c,n,h); grid = C*N*H/4 = 8192 blocks of 256
// ---------------------------------------------------------------------------
__global__ __launch_bounds__(256) void k_logits(const float* __restrict__ P,
                                                const float* __restrict__ asrc,
                                                const float* __restrict__ adst,
                                                float* __restrict__ a_src_o,
                                                float* __restrict__ a_dst_o) {
    int row  = blockIdx.x*4 + (threadIdx.x >> 6);   // [0, C*N*H)
    int lane = threadIdx.x & 63;
    int h = row & 3;
    int n = (row >> 2) & 1023;
    int c = row >> 12;
    int t_o = n >> 7;
    int q8  = (n & 127) * 8;

    const float* pb = P + ((size_t)(c*TT + t_o)*NN + q8)*KK + h*64 + lane;
    float s = 0.f, d = 0.f;
    #pragma unroll
    for (int e = 0; e < 8; ++e) {               // e == t2, lane == f2
        float pv = pb[(size_t)e*KK];
        s += pv * asrc[h*512 + e*64 + lane];
        d += pv * adst[h*512 + e*64 + lane];
    }
    #pragma unroll
    for (int m = 32; m; m >>= 1) { s += __shfl_xor(s, m); d += __shfl_xor(d, m); }
    if (lane == 0) { a_src_o[row] = s; a_dst_o[row] = d; }
}

// ---------------------------------------------------------------------------
// K3: adjacency bitset from flat edge indices (dedups duplicate edges)
// ---------------------------------------------------------------------------
__global__ __launch_bounds__(256) void k_adj(const int* __restrict__ ei,
                                             unsigned* __restrict__ adj) {
    int e = blockIdx.x*256 + threadIdx.x;
    if (e >= EE) return;
    int s = ei[e];
    int d = ei[EE + e];
    int c = s >> 10;
    int i = s & 1023;
    int j = d & 1023;
    atomicOr(&adj[((size_t)((c << 10) + j))*32 + (i >> 5)], 1u << (i & 31));
}

// ---------------------------------------------------------------------------
// K4: per-(c,j) softmax over in-neighbors + attn scatter + PV + head-mean
// grid = C*N blocks of 256 (4 waves = 4 heads)
// ---------------------------------------------------------------------------
__global__ __launch_bounds__(256) void k_attn(const float* __restrict__ P,
                                              const float* __restrict__ a_src,
                                              const float* __restrict__ a_dst,
                                              const unsigned* __restrict__ adj,
                                              float* __restrict__ out,
                                              float* __restrict__ attn_out) {
    __shared__ unsigned short L[256];
    __shared__ float attL[4][256];
    __shared__ int cnt;
    int bx = blockIdx.x;            // c*1024 + j
    int c = bx >> 10, j = bx & 1023;
    int tid = threadIdx.x;
    if (tid == 0) cnt = 0;
    __syncthreads();

    const unsigned* aw = adj + (size_t)bx*32;
    #pragma unroll
    for (int rep = 0; rep < 4; ++rep) {
        int i = tid + rep*256;
        if ((aw[i >> 5] >> (i & 31)) & 1u) {
            int pos = atomicAdd(&cnt, 1);
            if (pos < 256) L[pos] = (unsigned short)i;
        }
    }
    __syncthreads();
    int n = cnt; if (n > 256) n = 256;

    int h = tid >> 6, lane = tid & 63;
    float adv = a_dst[bx*4 + h];

    float m = -1e30f;
    for (int e = lane; e < n; e += 64) {
        int i = L[e];
        float z = a_src[((size_t)((c << 10) + i))*4 + h] + adv;
        z = (z < 0.f) ? 0.2f*z : z;          // leaky relu
        attL[h][e] = z;
        m = fmaxf(m, z);
    }
    #pragma unroll
    for (int mm = 32; mm; mm >>= 1) m = fmaxf(m, __shfl_xor(m, mm));

    float ssum = 0.f;
    for (int e = lane; e < n; e += 64) {
        float ez = expf(attL[h][e] - m);
        attL[h][e] = ez;
        ssum += ez;
    }
    #pragma unroll
    for (int mm = 32; mm; mm >>= 1) ssum += __shfl_xor(ssum, mm);
    float inv = (n > 0) ? 1.f / ssum : 0.f;

    for (int e = lane; e < n; e += 64) {
        float v = attL[h][e] * inv;
        attL[h][e] = v;
        attn_out[((size_t)((c << 10) + L[e])*1024 + j)*4 + h] = v;
    }
    __syncthreads();

    // PV + mean over heads: out[c,j,t2,f2] = 0.25 * sum_h sum_e attL[h][e]*P[...]
    #pragma unroll
    for (int rep = 0; rep < 2; ++rep) {
        int tf = tid + rep*256;
        int t2 = tf >> 6, f2 = tf & 63;
        float acc = 0.f;
        for (int e = 0; e < n; ++e) {
            int i = L[e];
            const float* pr = P + ((size_t)(c*TT + (i >> 7))*NN + (i & 127)*8 + t2)*KK + f2;
            acc += attL[0][e]*pr[0]  + attL[1][e]*pr[64]
                 + attL[2][e]*pr[128] + attL[3][e]*pr[192];
        }
        out[((size_t)bx*TT + t2)*FF + f2] = acc * 0.25f;
    }
}

// ---------------------------------------------------------------------------
extern "C" void kernel_launch(void* const* d_in, const int* in_sizes, int n_in,
                              void* d_out, int out_size, void* d_ws, size_t ws_size,
                              hipStream_t stream) {
    const int*   ei   = (const int*)d_in[0];
    const float* nf   = (const float*)d_in[1];
    const float* fc   = (const float*)d_in[2];
    const float* asrc = (const float*)d_in[3];
    const float* adst = (const float*)d_in[4];

    float* out      = (float*)d_out;
    float* attn_out = out + OUT_ELEMS;

    char* ws = (char*)d_ws;
    float*    P       = (float*)ws;
    float*    a_src_w = (float*)(ws + ASRC_OFF);
    float*    a_dst_w = (float*)(ws + ADST_OFF);
    unsigned* adjw    = (unsigned*)(ws + ADJ_OFF);

    hipMemsetAsync(attn_out, 0, ATTN_ELEMS*sizeof(float), stream);
    hipMemsetAsync(adjw, 0, (size_t)CC*NN*32*sizeof(unsigned), stream);

    k_proj  <<<CC*TT*16, 256, 0, stream>>>(nf, fc, P);
    k_logits<<<CC*NN*HH/4, 256, 0, stream>>>(P, asrc, adst, a_src_w, a_dst_w);
    k_adj   <<<EE/256, 256, 0, stream>>>(ei, adjw);
    k_attn  <<<CC*NN, 256, 0, stream>>>(P, a_src_w, a_dst_w, adjw, out, attn_out);
}

// Round 2
// 146.489 us; speedup vs baseline: 1.2532x; 1.2532x over previous
//
#include <hip/hip_runtime.h>

#define CC 8
#define NN 1024
#define TT 8
#define II 64
#define HH 4
#define FF 64
#define EE (CC*NN*16)          // 131072 edges
#define KK 256                 // F*H

static const size_t OUT_ELEMS  = (size_t)CC*NN*TT*FF;     // 4,194,304
static const size_t ATTN_ELEMS = (size_t)CC*NN*NN*HH;     // 33,554,432

// ws layout (bytes)
//  Pg   : [C][N][t2][f2][h] bf16  -> 33,554,432
//  a_src: [C][N][H] f32           ->    131,072
//  a_dst: [C][N][H] f32           ->    131,072
//  soff : [C][N][H] f32 (m+log s) ->    131,072
//  adj  : [C][j][32] u32 (bits i) ->  1,048,576
//  adjT : [C][i][32] u32 (bits j) ->  1,048,576
static const size_t PG_OFF   = 0;
static const size_t ASRC_OFF = 33554432;
static const size_t ADST_OFF = ASRC_OFF + 131072;
static const size_t SOFF_OFF = ADST_OFF + 131072;
static const size_t ADJ_OFF  = SOFF_OFF + 131072;
static const size_t ADJT_OFF = ADJ_OFF + 1048576;

static __device__ inline unsigned short f2bf(float x) {
    union { float f; unsigned u; } q; q.f = x;
    unsigned r = q.u + 0x7fffu + ((q.u >> 16) & 1u);   // RNE
    return (unsigned short)(r >> 16);
}
static __device__ inline float bf2f(unsigned short u) {
    return __uint_as_float(((unsigned)u) << 16);
}

// ---------------------------------------------------------------------------
// K1: fused projection + bf16 feat3-layout store + attention-logit vectors
// block = (c, t, 32-row tile) ; grid = 8*8*32 = 2048, 256 threads
// P[c][t][r][k] = sum_i nf[c,n0+r,t,i] * fc[t,i,k]
// node n2 = t*128 + tile*4 + (r>>3), t2 = r&7, h = k>>6, f2 = k&63
// ---------------------------------------------------------------------------
__global__ __launch_bounds__(256) void k1_proj(const float* __restrict__ nf,
                                               const float* __restrict__ fc,
                                               const float* __restrict__ avs,
                                               const float* __restrict__ avd,
                                               unsigned short* __restrict__ Pg,
                                               float* __restrict__ a_src,
                                               float* __restrict__ a_dst) {
    __shared__ float fcs[64*128];      // 32 KB, one half of fc[t]
    __shared__ float nfs[64*36];       // i-major, padded (9.2 KB)
    __shared__ float sh_a[2][4][4];    // [src/dst][node][h]
    int bx = blockIdx.x;
    int c = bx & 7;
    int rem = bx >> 3;
    int t = rem >> 5;
    int tile = rem & 31;
    int n0 = tile * 32;
    int tid = threadIdx.x;
    int ci = tid & 31;                 // 4 cols: ci*4..ci*4+3 within half
    int rg = tid >> 5;                 // 4 rows: rg*4..rg*4+3
    int node = rg >> 1;

    if (tid < 32) ((float*)sh_a)[tid] = 0.f;

    for (int l = tid; l < 32*64; l += 256) {
        int r = l >> 6, i = l & 63;
        nfs[i*36 + r] = nf[((size_t)(c*NN + n0 + r)*TT + t)*II + i];
    }

    float acc[2][4][4];
    #pragma unroll
    for (int hf = 0; hf < 2; ++hf)
        #pragma unroll
        for (int v = 0; v < 4; ++v)
            #pragma unroll
            for (int u = 0; u < 4; ++u) acc[hf][v][u] = 0.f;

    #pragma unroll
    for (int half = 0; half < 2; ++half) {
        __syncthreads();
        for (int l = tid; l < 64*128; l += 256) {
            int i = l >> 7, kk = l & 127;
            fcs[l] = fc[(size_t)(t*64 + i)*KK + half*128 + kk];
        }
        __syncthreads();
        for (int i = 0; i < 64; ++i) {
            float4 aa = *(const float4*)&nfs[i*36 + rg*4];
            float4 bb = *(const float4*)&fcs[i*128 + ci*4];
            float av[4] = {aa.x, aa.y, aa.z, aa.w};
            float bu[4] = {bb.x, bb.y, bb.z, bb.w};
            #pragma unroll
            for (int v = 0; v < 4; ++v)
                #pragma unroll
                for (int u = 0; u < 4; ++u) acc[half][v][u] += av[v]*bu[u];
        }
    }

    // ---- logit partial sums: a = sum_{t2,f2} P * avec[h*512 + t2*64 + f2]
    #pragma unroll
    for (int half = 0; half < 2; ++half) {
        int kb = half*128 + ci*4;
        int h = kb >> 6;
        int f2b = kb & 63;
        float ps = 0.f, pd = 0.f;
        #pragma unroll
        for (int v = 0; v < 4; ++v) {
            int t2 = (rg & 1)*4 + v;
            float4 s4 = *(const float4*)&avs[h*512 + t2*64 + f2b];
            float4 d4 = *(const float4*)&avd[h*512 + t2*64 + f2b];
            ps += acc[half][v][0]*s4.x + acc[half][v][1]*s4.y
                + acc[half][v][2]*s4.z + acc[half][v][3]*s4.w;
            pd += acc[half][v][0]*d4.x + acc[half][v][1]*d4.y
                + acc[half][v][2]*d4.z + acc[half][v][3]*d4.w;
        }
        atomicAdd(&sh_a[0][node][h], ps);
        atomicAdd(&sh_a[1][node][h], pd);
    }

    // ---- stage bf16 feat3 layout into LDS (reuse fcs), then coalesced copy
    __syncthreads();
    unsigned short* stg = (unsigned short*)fcs;   // 16 KB used
    #pragma unroll
    for (int half = 0; half < 2; ++half) {
        int kb = half*128 + ci*4;
        int h = kb >> 6;
        int f2b = kb & 63;
        #pragma unroll
        for (int v = 0; v < 4; ++v) {
            int t2 = (rg & 1)*4 + v;
            int base = node*2048 + t2*256 + f2b*4 + h;
            stg[base]      = f2bf(acc[half][v][0]);
            stg[base + 4]  = f2bf(acc[half][v][1]);
            stg[base + 8]  = f2bf(acc[half][v][2]);
            stg[base + 12] = f2bf(acc[half][v][3]);
        }
    }
    __syncthreads();
    {
        const uint4* s4p = (const uint4*)stg;
        uint4* g4 = (uint4*)(Pg + ((size_t)(c*NN) + t*128 + tile*4) * 2048);
        for (int l = tid; l < 1024; l += 256) g4[l] = s4p[l];
        if (tid < 16) {
            int nd = tid >> 2, h = tid & 3;
            int n2 = t*128 + tile*4 + nd;
            a_src[(size_t)(c*NN + n2)*HH + h] = sh_a[0][nd][h];
            a_dst[(size_t)(c*NN + n2)*HH + h] = sh_a[1][nd][h];
        }
    }
}

// ---------------------------------------------------------------------------
// K2: adjacency bitsets (dst-major and src-major)
// ---------------------------------------------------------------------------
__global__ __launch_bounds__(256) void k_adj(const int* __restrict__ ei,
                                             unsigned* __restrict__ adj,
                                             unsigned* __restrict__ adjT) {
    int e = blockIdx.x*256 + threadIdx.x;
    if (e >= EE) return;
    int s = ei[e];
    int d = ei[EE + e];
    int c = s >> 10;
    int i = s & 1023;
    int j = d & 1023;
    atomicOr(&adj [((size_t)((c << 10) + j))*32 + (i >> 5)], 1u << (i & 31));
    atomicOr(&adjT[((size_t)((c << 10) + i))*32 + (j >> 5)], 1u << (j & 31));
}

// ---------------------------------------------------------------------------
// K3: per-(c,j): list build + softmax stats (writes soff) + PV + head-mean
// grid = C*N, c = blockIdx&7 (XCD-pinned conformer), 256 threads (wave per h)
// ---------------------------------------------------------------------------
__global__ __launch_bounds__(256) void k5_attn(const unsigned short* __restrict__ Pg,
                                               const float* __restrict__ a_src,
                                               const float* __restrict__ a_dst,
                                               const unsigned* __restrict__ adj,
                                               float* __restrict__ soff,
                                               float* __restrict__ out) {
    __shared__ unsigned short L[128];
    __shared__ float attL[4][128];
    __shared__ int cnt;
    int bx = blockIdx.x;
    int c = bx & 7, j = bx >> 3;
    int cb = c << 10;
    int tid = threadIdx.x;
    if (tid == 0) cnt = 0;
    __syncthreads();

    const unsigned* aw = adj + (size_t)(cb + j)*32;
    #pragma unroll
    for (int rep = 0; rep < 4; ++rep) {
        int i = rep*256 + tid;
        if ((aw[i >> 5] >> (i & 31)) & 1u) {
            int pos = atomicAdd(&cnt, 1);
            if (pos < 128) L[pos] = (unsigned short)i;
        }
    }
    __syncthreads();
    int n = cnt; if (n > 128) n = 128;

    int h = tid >> 6, lane = tid & 63;
    float adv = a_dst[(size_t)(cb + j)*4 + h];

    float m = -1e30f;
    for (int e = lane; e < n; e += 64) {
        int i = L[e];
        float z = a_src[(size_t)(cb + i)*4 + h] + adv;
        z = (z < 0.f) ? 0.2f*z : z;          // leaky relu
        attL[h][e] = z;
        m = fmaxf(m, z);
    }
    #pragma unroll
    for (int mm = 32; mm; mm >>= 1) m = fmaxf(m, __shfl_xor(m, mm));
    float ssum = 0.f;
    for (int e = lane; e < n; e += 64) {
        float ez = __expf(attL[h][e] - m);
        attL[h][e] = ez;
        ssum += ez;
    }
    #pragma unroll
    for (int mm = 32; mm; mm >>= 1) ssum += __shfl_xor(ssum, mm);
    if (lane == 0) soff[(size_t)(cb + j)*4 + h] = m + __logf(ssum);
    float inv = 1.f / ssum;
    for (int e = lane; e < n; e += 64) attL[h][e] *= inv;
    __syncthreads();

    // PV: out[c,j,tf] = 0.25 * sum_h sum_e attL[h][e] * Pg[c][i][tf*4+h]
    #pragma unroll
    for (int rep = 0; rep < 2; ++rep) {
        int tf = rep*256 + tid;
        float acc = 0.f;
        for (int e = 0; e < n; ++e) {
            int i = L[e];
            uint2 pv = *(const uint2*)(Pg + ((size_t)(cb + i)*2048 + tf*4));
            acc += attL[0][e]*bf2f((unsigned short)(pv.x & 0xffffu))
                 + attL[1][e]*bf2f((unsigned short)(pv.x >> 16))
                 + attL[2][e]*bf2f((unsigned short)(pv.y & 0xffffu))
                 + attL[3][e]*bf2f((unsigned short)(pv.y >> 16));
        }
        out[(size_t)(cb + j)*512 + tf] = acc * 0.25f;
    }
}

// ---------------------------------------------------------------------------
// K4: dense attn writer — one block per (c,i) row, writes 16 KB coalesced
// attn[c][i][j][h] = edge ? exp(leaky(a_src+a_dst) - soff[c,j,h]) : 0
// ---------------------------------------------------------------------------
__global__ __launch_bounds__(256) void k4_attnw(const float* __restrict__ a_src,
                                                const float* __restrict__ a_dst,
                                                const float* __restrict__ soff,
                                                const unsigned* __restrict__ adjT,
                                                float* __restrict__ attn_out) {
    int bx = blockIdx.x;
    int c = bx & 7, i = bx >> 3;
    int cb = c << 10;
    int tid = threadIdx.x;
    const unsigned* aw = adjT + (size_t)(cb + i)*32;
    float as0 = a_src[(size_t)(cb + i)*4 + 0];
    float as1 = a_src[(size_t)(cb + i)*4 + 1];
    float as2 = a_src[(size_t)(cb + i)*4 + 2];
    float as3 = a_src[(size_t)(cb + i)*4 + 3];
    float* dst = attn_out + (size_t)(cb + i)*4096;
    #pragma unroll 4
    for (int it = 0; it < 16; ++it) {
        int jh = it*256 + tid;
        int j = jh >> 2, h = jh & 3;
        float val = 0.f;
        if ((aw[j >> 5] >> (j & 31)) & 1u) {
            float as = (h == 0) ? as0 : (h == 1) ? as1 : (h == 2) ? as2 : as3;
            float z = as + a_dst[(size_t)(cb + j)*4 + h];
            z = (z < 0.f) ? 0.2f*z : z;
            val = __expf(z - soff[(size_t)(cb + j)*4 + h]);
        }
        dst[jh] = val;
    }
}

// ---------------------------------------------------------------------------
extern "C" void kernel_launch(void* const* d_in, const int* in_sizes, int n_in,
                              void* d_out, int out_size, void* d_ws, size_t ws_size,
                              hipStream_t stream) {
    const int*   ei   = (const int*)d_in[0];
    const float* nf   = (const float*)d_in[1];
    const float* fc   = (const float*)d_in[2];
    const float* avs  = (const float*)d_in[3];
    const float* avd  = (const float*)d_in[4];

    float* out      = (float*)d_out;
    float* attn_out = out + OUT_ELEMS;

    char* ws = (char*)d_ws;
    unsigned short* Pg      = (unsigned short*)(ws + PG_OFF);
    float*          a_src_w = (float*)(ws + ASRC_OFF);
    float*          a_dst_w = (float*)(ws + ADST_OFF);
    float*          soff_w  = (float*)(ws + SOFF_OFF);
    unsigned*       adjw    = (unsigned*)(ws + ADJ_OFF);
    unsigned*       adjTw   = (unsigned*)(ws + ADJT_OFF);

    hipMemsetAsync(ws + ADJ_OFF, 0, 2*1048576, stream);

    k1_proj <<<2048, 256, 0, stream>>>(nf, fc, avs, avd, Pg, a_src_w, a_dst_w);
    k_adj   <<<EE/256, 256, 0, stream>>>(ei, adjw, adjTw);
    k5_attn <<<CC*NN, 256, 0, stream>>>(Pg, a_src_w, a_dst_w, adjw, soff_w, out);
    k4_attnw<<<CC*NN, 256, 0, stream>>>(a_src_w, a_dst_w, soff_w, adjTw, attn_out);
}

// Round 3
// 145.595 us; speedup vs baseline: 1.2609x; 1.0061x over previous
//
#include <hip/hip_runtime.h>

#define CC 8
#define NN 1024
#define TT 8
#define II 64
#define HH 4
#define FF 64
#define EE (CC*NN*16)          // 131072 edges
#define KK 256                 // F*H

static const size_t OUT_ELEMS  = (size_t)CC*NN*TT*FF;     // 4,194,304
static const size_t ATTN_ELEMS = (size_t)CC*NN*NN*HH;     // 33,554,432

// ws layout (bytes)
//  Pg   : [C][N][t2][f2][h] bf16  -> 33,554,432
//  a_src: [C][N][H] f32           ->    131,072
//  a_dst: [C][N][H] f32           ->    131,072
//  soff : [C][N][H] f32 (m+log s) ->    131,072
//  adj  : [C][j][32] u32 (bits i) ->  1,048,576
//  adjT : [C][i][32] u32 (bits j) ->  1,048,576
static const size_t PG_OFF   = 0;
static const size_t ASRC_OFF = 33554432;
static const size_t ADST_OFF = ASRC_OFF + 131072;
static const size_t SOFF_OFF = ADST_OFF + 131072;
static const size_t ADJ_OFF  = SOFF_OFF + 131072;
static const size_t ADJT_OFF = ADJ_OFF + 1048576;

static __device__ inline unsigned short f2bf(float x) {
    union { float f; unsigned u; } q; q.f = x;
    unsigned r = q.u + 0x7fffu + ((q.u >> 16) & 1u);   // RNE
    return (unsigned short)(r >> 16);
}
static __device__ inline float bf2f(unsigned short u) {
    return __uint_as_float(((unsigned)u) << 16);
}

// ---------------------------------------------------------------------------
// K0: zero the 2 MB adjacency region (custom — runtime fillBuffer was 91 µs!)
// 512 blocks * 256 threads * 16 B = 2,097,152 B
// ---------------------------------------------------------------------------
__global__ __launch_bounds__(256) void k0_zero(uint4* __restrict__ p) {
    p[blockIdx.x*256 + threadIdx.x] = make_uint4(0u, 0u, 0u, 0u);
}

// ---------------------------------------------------------------------------
// K1: fused projection + bf16 feat3-layout store + attention-logit vectors
// block = (c, t, 32-row tile) ; grid = 8*8*32 = 2048, 256 threads
// P[c][t][r][k] = sum_i nf[c,n0+r,t,i] * fc[t,i,k]
// node n2 = t*128 + tile*4 + (r>>3), t2 = r&7, h = k>>6, f2 = k&63
// ---------------------------------------------------------------------------
__global__ __launch_bounds__(256) void k1_proj(const float* __restrict__ nf,
                                               const float* __restrict__ fc,
                                               const float* __restrict__ avs,
                                               const float* __restrict__ avd,
                                               unsigned short* __restrict__ Pg,
                                               float* __restrict__ a_src,
                                               float* __restrict__ a_dst) {
    __shared__ float fcs[64*128];      // 32 KB, one half of fc[t]
    __shared__ float nfs[64*36];       // i-major, padded (9.2 KB)
    __shared__ float sh_a[2][4][4];    // [src/dst][node][h]
    int bx = blockIdx.x;
    int c = bx & 7;
    int rem = bx >> 3;
    int t = rem >> 5;
    int tile = rem & 31;
    int n0 = tile * 32;
    int tid = threadIdx.x;
    int ci = tid & 31;                 // 4 cols: ci*4..ci*4+3 within half
    int rg = tid >> 5;                 // 4 rows: rg*4..rg*4+3
    int node = rg >> 1;

    if (tid < 32) ((float*)sh_a)[tid] = 0.f;

    for (int l = tid; l < 32*64; l += 256) {
        int r = l >> 6, i = l & 63;
        nfs[i*36 + r] = nf[((size_t)(c*NN + n0 + r)*TT + t)*II + i];
    }

    float acc[2][4][4];
    #pragma unroll
    for (int hf = 0; hf < 2; ++hf)
        #pragma unroll
        for (int v = 0; v < 4; ++v)
            #pragma unroll
            for (int u = 0; u < 4; ++u) acc[hf][v][u] = 0.f;

    #pragma unroll
    for (int half = 0; half < 2; ++half) {
        __syncthreads();
        for (int l = tid; l < 64*128; l += 256) {
            int i = l >> 7, kk = l & 127;
            fcs[l] = fc[(size_t)(t*64 + i)*KK + half*128 + kk];
        }
        __syncthreads();
        for (int i = 0; i < 64; ++i) {
            float4 aa = *(const float4*)&nfs[i*36 + rg*4];
            float4 bb = *(const float4*)&fcs[i*128 + ci*4];
            float av[4] = {aa.x, aa.y, aa.z, aa.w};
            float bu[4] = {bb.x, bb.y, bb.z, bb.w};
            #pragma unroll
            for (int v = 0; v < 4; ++v)
                #pragma unroll
                for (int u = 0; u < 4; ++u) acc[half][v][u] += av[v]*bu[u];
        }
    }

    // ---- logit partial sums: a = sum_{t2,f2} P * avec[h*512 + t2*64 + f2]
    #pragma unroll
    for (int half = 0; half < 2; ++half) {
        int kb = half*128 + ci*4;
        int h = kb >> 6;
        int f2b = kb & 63;
        float ps = 0.f, pd = 0.f;
        #pragma unroll
        for (int v = 0; v < 4; ++v) {
            int t2 = (rg & 1)*4 + v;
            float4 s4 = *(const float4*)&avs[h*512 + t2*64 + f2b];
            float4 d4 = *(const float4*)&avd[h*512 + t2*64 + f2b];
            ps += acc[half][v][0]*s4.x + acc[half][v][1]*s4.y
                + acc[half][v][2]*s4.z + acc[half][v][3]*s4.w;
            pd += acc[half][v][0]*d4.x + acc[half][v][1]*d4.y
                + acc[half][v][2]*d4.z + acc[half][v][3]*d4.w;
        }
        atomicAdd(&sh_a[0][node][h], ps);
        atomicAdd(&sh_a[1][node][h], pd);
    }

    // ---- stage bf16 feat3 layout into LDS (reuse fcs), then coalesced copy
    __syncthreads();
    unsigned short* stg = (unsigned short*)fcs;   // 16 KB used
    #pragma unroll
    for (int half = 0; half < 2; ++half) {
        int kb = half*128 + ci*4;
        int h = kb >> 6;
        int f2b = kb & 63;
        #pragma unroll
        for (int v = 0; v < 4; ++v) {
            int t2 = (rg & 1)*4 + v;
            int base = node*2048 + t2*256 + f2b*4 + h;
            stg[base]      = f2bf(acc[half][v][0]);
            stg[base + 4]  = f2bf(acc[half][v][1]);
            stg[base + 8]  = f2bf(acc[half][v][2]);
            stg[base + 12] = f2bf(acc[half][v][3]);
        }
    }
    __syncthreads();
    {
        const uint4* s4p = (const uint4*)stg;
        uint4* g4 = (uint4*)(Pg + ((size_t)(c*NN) + t*128 + tile*4) * 2048);
        for (int l = tid; l < 1024; l += 256) g4[l] = s4p[l];
        if (tid < 16) {
            int nd = tid >> 2, h = tid & 3;
            int n2 = t*128 + tile*4 + nd;
            a_src[(size_t)(c*NN + n2)*HH + h] = sh_a[0][nd][h];
            a_dst[(size_t)(c*NN + n2)*HH + h] = sh_a[1][nd][h];
        }
    }
}

// ---------------------------------------------------------------------------
// K2: adjacency bitsets (dst-major and src-major)
// ---------------------------------------------------------------------------
__global__ __launch_bounds__(256) void k_adj(const int* __restrict__ ei,
                                             unsigned* __restrict__ adj,
                                             unsigned* __restrict__ adjT) {
    int e = blockIdx.x*256 + threadIdx.x;
    if (e >= EE) return;
    int s = ei[e];
    int d = ei[EE + e];
    int c = s >> 10;
    int i = s & 1023;
    int j = d & 1023;
    atomicOr(&adj [((size_t)((c << 10) + j))*32 + (i >> 5)], 1u << (i & 31));
    atomicOr(&adjT[((size_t)((c << 10) + i))*32 + (j >> 5)], 1u << (j & 31));
}

// ---------------------------------------------------------------------------
// K3: per-(c,j): list build + softmax stats (writes soff) + PV + head-mean
// grid = C*N, c = blockIdx&7 (XCD-pinned conformer), 256 threads (wave per h)
// ---------------------------------------------------------------------------
__global__ __launch_bounds__(256) void k5_attn(const unsigned short* __restrict__ Pg,
                                               const float* __restrict__ a_src,
                                               const float* __restrict__ a_dst,
                                               const unsigned* __restrict__ adj,
                                               float* __restrict__ soff,
                                               float* __restrict__ out) {
    __shared__ unsigned short L[128];
    __shared__ float attL[4][128];
    __shared__ int cnt;
    int bx = blockIdx.x;
    int c = bx & 7, j = bx >> 3;
    int cb = c << 10;
    int tid = threadIdx.x;
    if (tid == 0) cnt = 0;
    __syncthreads();

    const unsigned* aw = adj + (size_t)(cb + j)*32;
    #pragma unroll
    for (int rep = 0; rep < 4; ++rep) {
        int i = rep*256 + tid;
        if ((aw[i >> 5] >> (i & 31)) & 1u) {
            int pos = atomicAdd(&cnt, 1);
            if (pos < 128) L[pos] = (unsigned short)i;
        }
    }
    __syncthreads();
    int n = cnt; if (n > 128) n = 128;

    int h = tid >> 6, lane = tid & 63;
    float adv = a_dst[(size_t)(cb + j)*4 + h];

    float m = -1e30f;
    for (int e = lane; e < n; e += 64) {
        int i = L[e];
        float z = a_src[(size_t)(cb + i)*4 + h] + adv;
        z = (z < 0.f) ? 0.2f*z : z;          // leaky relu
        attL[h][e] = z;
        m = fmaxf(m, z);
    }
    #pragma unroll
    for (int mm = 32; mm; mm >>= 1) m = fmaxf(m, __shfl_xor(m, mm));
    float ssum = 0.f;
    for (int e = lane; e < n; e += 64) {
        float ez = __expf(attL[h][e] - m);
        attL[h][e] = ez;
        ssum += ez;
    }
    #pragma unroll
    for (int mm = 32; mm; mm >>= 1) ssum += __shfl_xor(ssum, mm);
    if (lane == 0) soff[(size_t)(cb + j)*4 + h] = m + __logf(ssum);
    float inv = 1.f / ssum;
    for (int e = lane; e < n; e += 64) attL[h][e] *= inv;
    __syncthreads();

    // PV: out[c,j,tf] = 0.25 * sum_h sum_e attL[h][e] * Pg[c][i][tf*4+h]
    #pragma unroll
    for (int rep = 0; rep < 2; ++rep) {
        int tf = rep*256 + tid;
        float acc = 0.f;
        for (int e = 0; e < n; ++e) {
            int i = L[e];
            uint2 pv = *(const uint2*)(Pg + ((size_t)(cb + i)*2048 + tf*4));
            acc += attL[0][e]*bf2f((unsigned short)(pv.x & 0xffffu))
                 + attL[1][e]*bf2f((unsigned short)(pv.x >> 16))
                 + attL[2][e]*bf2f((unsigned short)(pv.y & 0xffffu))
                 + attL[3][e]*bf2f((unsigned short)(pv.y >> 16));
        }
        out[(size_t)(cb + j)*512 + tf] = acc * 0.25f;
    }
}

// ---------------------------------------------------------------------------
// K4: dense attn writer — one block per (c,i) row, writes 16 KB coalesced
// attn[c][i][j][h] = edge ? exp(leaky(a_src+a_dst) - soff[c,j,h]) : 0
// ---------------------------------------------------------------------------
__global__ __launch_bounds__(256) void k4_attnw(const float* __restrict__ a_src,
                                                const float* __restrict__ a_dst,
                                                const float* __restrict__ soff,
                                                const unsigned* __restrict__ adjT,
                                                float* __restrict__ attn_out) {
    int bx = blockIdx.x;
    int c = bx & 7, i = bx >> 3;
    int cb = c << 10;
    int tid = threadIdx.x;
    const unsigned* aw = adjT + (size_t)(cb + i)*32;
    float as0 = a_src[(size_t)(cb + i)*4 + 0];
    float as1 = a_src[(size_t)(cb + i)*4 + 1];
    float as2 = a_src[(size_t)(cb + i)*4 + 2];
    float as3 = a_src[(size_t)(cb + i)*4 + 3];
    float* dst = attn_out + (size_t)(cb + i)*4096;
    #pragma unroll 4
    for (int it = 0; it < 16; ++it) {
        int jh = it*256 + tid;
        int j = jh >> 2, h = jh & 3;
        float val = 0.f;
        if ((aw[j >> 5] >> (j & 31)) & 1u) {
            float as = (h == 0) ? as0 : (h == 1) ? as1 : (h == 2) ? as2 : as3;
            float z = as + a_dst[(size_t)(cb + j)*4 + h];
            z = (z < 0.f) ? 0.2f*z : z;
            val = __expf(z - soff[(size_t)(cb + j)*4 + h]);
        }
        dst[jh] = val;
    }
}

// ---------------------------------------------------------------------------
extern "C" void kernel_launch(void* const* d_in, const int* in_sizes, int n_in,
                              void* d_out, int out_size, void* d_ws, size_t ws_size,
                              hipStream_t stream) {
    const int*   ei   = (const int*)d_in[0];
    const float* nf   = (const float*)d_in[1];
    const float* fc   = (const float*)d_in[2];
    const float* avs  = (const float*)d_in[3];
    const float* avd  = (const float*)d_in[4];

    float* out      = (float*)d_out;
    float* attn_out = out + OUT_ELEMS;

    char* ws = (char*)d_ws;
    unsigned short* Pg      = (unsigned short*)(ws + PG_OFF);
    float*          a_src_w = (float*)(ws + ASRC_OFF);
    float*          a_dst_w = (float*)(ws + ADST_OFF);
    float*          soff_w  = (float*)(ws + SOFF_OFF);
    unsigned*       adjw    = (unsigned*)(ws + ADJ_OFF);
    unsigned*       adjTw   = (unsigned*)(ws + ADJT_OFF);

    k0_zero <<<512, 256, 0, stream>>>((uint4*)(ws + ADJ_OFF));
    k1_proj <<<2048, 256, 0, stream>>>(nf, fc, avs, avd, Pg, a_src_w, a_dst_w);
    k_adj   <<<EE/256, 256, 0, stream>>>(ei, adjw, adjTw);
    k5_attn <<<CC*NN, 256, 0, stream>>>(Pg, a_src_w, a_dst_w, adjw, soff_w, out);
    k4_attnw<<<CC*NN, 256, 0, stream>>>(a_src_w, a_dst_w, soff_w, adjTw, attn_out);
}

// Round 4
// 118.876 us; speedup vs baseline: 1.5443x; 1.2248x over previous
//
#include <hip/hip_runtime.h>

typedef short  bf16x8 __attribute__((ext_vector_type(8)));
typedef float  f32x4  __attribute__((ext_vector_type(4)));

#define CC 8
#define NN 1024
#define TT 8
#define II 64
#define HH 4
#define FF 64
#define EE (CC*NN*16)          // 131072 edges
#define KK 256                 // F*H

static const size_t OUT_ELEMS  = (size_t)CC*NN*TT*FF;     // 4,194,304
static const size_t ATTN_ELEMS = (size_t)CC*NN*NN*HH;     // 33,554,432

// ws layout (bytes)
//  Pg   : [C][N][t2][f2][h] bf16  -> 33,554,432
//  a_src: [C][N][H] f32           ->    131,072
//  a_dst: [C][N][H] f32           ->    131,072
//  soff : [C][N][H] f32 (m+log s) ->    131,072
//  adj  : [C][j][32] u32 (bits i) ->  1,048,576
//  adjT : [C][i][32] u32 (bits j) ->  1,048,576
//  fcT  : [T][k][i] bf16          ->    262,144
static const size_t PG_OFF   = 0;
static const size_t ASRC_OFF = 33554432;
static const size_t ADST_OFF = ASRC_OFF + 131072;
static const size_t SOFF_OFF = ADST_OFF + 131072;
static const size_t ADJ_OFF  = SOFF_OFF + 131072;
static const size_t ADJT_OFF = ADJ_OFF + 1048576;
static const size_t FCT_OFF  = ADJT_OFF + 1048576;

static __device__ inline unsigned short f2bf(float x) {
    union { float f; unsigned u; } q; q.f = x;
    unsigned r = q.u + 0x7fffu + ((q.u >> 16) & 1u);   // RNE
    return (unsigned short)(r >> 16);
}
static __device__ inline float bf2f(unsigned short u) {
    return __uint_as_float(((unsigned)u) << 16);
}

// ---------------------------------------------------------------------------
// K0: zero 2 MB adjacency region + transpose fc -> fcT[t][k][i] bf16
// blocks 0..511: zero (512*256*16B = 2 MiB); blocks 512..639: transpose
// ---------------------------------------------------------------------------
__global__ __launch_bounds__(256) void k0_prep(const float* __restrict__ fc,
                                               unsigned short* __restrict__ fcT,
                                               uint4* __restrict__ adjz) {
    int bx = blockIdx.x;
    int tid = threadIdx.x;
    if (bx < 512) {
        adjz[bx*256 + tid] = make_uint4(0u, 0u, 0u, 0u);
    } else {
        int gid = (bx - 512)*256 + tid;     // 32768 threads, 4 elems each
        int e0 = gid*4;                     // flat [t][k][i], i fastest
        int i0 = e0 & 63;
        int k  = (e0 >> 6) & 255;
        int t  = e0 >> 14;
        unsigned short v0 = f2bf(fc[(size_t)(t*64 + i0    )*KK + k]);
        unsigned short v1 = f2bf(fc[(size_t)(t*64 + i0 + 1)*KK + k]);
        unsigned short v2 = f2bf(fc[(size_t)(t*64 + i0 + 2)*KK + k]);
        unsigned short v3 = f2bf(fc[(size_t)(t*64 + i0 + 3)*KK + k]);
        uint2 pk;
        pk.x = (unsigned)v0 | ((unsigned)v1 << 16);
        pk.y = (unsigned)v2 | ((unsigned)v3 << 16);
        *(uint2*)&fcT[e0] = pk;
    }
}

// ---------------------------------------------------------------------------
// K1: MFMA projection + bf16 feat3-layout store + f32-precision logits
// grid = 8c * 8t * 16 rowtiles = 1024 blocks, 256 threads (4 waves)
// block computes P-rows [tile*64, tile*64+64) x 256 cols for slice (c,t)
// wave w owns rows w*16..w*16+15, all 256 cols (16 col-tiles x K=64)
// MFMA frag maps (consistent A/B k-permutation): A[row=l&15][k=(l>>4)*8+j],
// B[k][col=l&15]; C: row=(l>>4)*4+v, col=l&15  [HW-verified m89]
// ---------------------------------------------------------------------------
__global__ __launch_bounds__(256) void k1_mfma(const float* __restrict__ nf,
                                               const unsigned short* __restrict__ fcT,
                                               const float* __restrict__ avs,
                                               const float* __restrict__ avd,
                                               unsigned short* __restrict__ Pg,
                                               float* __restrict__ a_src,
                                               float* __restrict__ a_dst) {
    __shared__ unsigned short stg[8*2048];     // 32 KB: 8 nodes x [t2][f2][h]
    __shared__ float avsL[2048];               // [h][ctl][col][t2]
    __shared__ float avdL[2048];
    int bx = blockIdx.x;
    int c = bx & 7, t = (bx >> 3) & 7, tile = bx >> 6;
    int tid = threadIdx.x;
    int w = tid >> 6, lane = tid & 63;
    int col = lane & 15, g = lane >> 4;

    // stage avec in swizzled layout: avsL[((h*4+ctl)*16+col)*8 + t2]
    for (int l = tid; l < 2048; l += 256) {
        int t2 = l & 7, cl = (l >> 3) & 15, ctl = (l >> 7) & 3, h = l >> 9;
        int si = h*512 + t2*64 + ctl*16 + cl;
        avsL[l] = avs[si];
        avdL[l] = avd[si];
    }

    // ---- A fragments: rows tile*64 + w*16 + (l&15), k = ks*32 + g*8 (+j)
    int row = tile*64 + w*16 + col;
    const float* ap = nf + ((size_t)(c*NN + row)*TT + t)*II + g*8;
    bf16x8 afr[2];
    #pragma unroll
    for (int ks = 0; ks < 2; ++ks) {
        float4 x = *(const float4*)(ap + ks*32);
        float4 y = *(const float4*)(ap + ks*32 + 4);
        afr[ks][0] = (short)f2bf(x.x); afr[ks][1] = (short)f2bf(x.y);
        afr[ks][2] = (short)f2bf(x.z); afr[ks][3] = (short)f2bf(x.w);
        afr[ks][4] = (short)f2bf(y.x); afr[ks][5] = (short)f2bf(y.y);
        afr[ks][6] = (short)f2bf(y.z); afr[ks][7] = (short)f2bf(y.w);
    }

    // ---- B fragments direct from fcT (L2-resident, 16B contiguous) + MFMA
    const unsigned short* bp = fcT + (size_t)t*256*64 + col*64 + g*8;
    f32x4 acc[16];
    #pragma unroll
    for (int ct = 0; ct < 16; ++ct) {
        bf16x8 b0 = *(const bf16x8*)(bp + (size_t)ct*16*64);
        bf16x8 b1 = *(const bf16x8*)(bp + (size_t)ct*16*64 + 32);
        f32x4 a; a[0] = 0.f; a[1] = 0.f; a[2] = 0.f; a[3] = 0.f;
        a = __builtin_amdgcn_mfma_f32_16x16x32_bf16(afr[0], b0, a, 0, 0, 0);
        a = __builtin_amdgcn_mfma_f32_16x16x32_bf16(afr[1], b1, a, 0, 0, 0);
        acc[ct] = a;
    }

    // ---- scatter C frags into stg (bf16, feat3 scramble), b64 writes
    // lane's rows: r = 4g+v -> node = w*2 + (g>>1), t2 = 4*(g&1)+v
    // k = ct*16+col -> h = ct>>2, f2 = (ct&3)*16+col
    int nd = w*2 + (g >> 1);
    int t2b = (g & 1)*4;
    #pragma unroll
    for (int ctl = 0; ctl < 4; ++ctl) {
        int f2 = ctl*16 + col;
        #pragma unroll
        for (int v = 0; v < 4; ++v) {
            unsigned u0 = (unsigned)f2bf(acc[ctl     ][v]) | ((unsigned)f2bf(acc[ 4+ctl][v]) << 16);
            unsigned u1 = (unsigned)f2bf(acc[ 8+ctl][v]) | ((unsigned)f2bf(acc[12+ctl][v]) << 16);
            *(uint2*)&stg[nd*2048 + (t2b + v)*256 + f2*4] = make_uint2(u0, u1);
        }
    }

    __syncthreads();   // avsL ready for reads; stg complete for copy-out

    // ---- logits from f32 accumulators: a[n2,h] = sum_{t2,f2} P * avec
    #pragma unroll
    for (int h = 0; h < 4; ++h) {
        float s = 0.f, d = 0.f;
        #pragma unroll
        for (int ctl = 0; ctl < 4; ++ctl) {
            float4 wS = *(const float4*)&avsL[((h*4 + ctl)*16 + col)*8 + t2b];
            float4 wD = *(const float4*)&avdL[((h*4 + ctl)*16 + col)*8 + t2b];
            f32x4 a = acc[h*4 + ctl];
            s += a[0]*wS.x + a[1]*wS.y + a[2]*wS.z + a[3]*wS.w;
            d += a[0]*wD.x + a[1]*wD.y + a[2]*wD.z + a[3]*wD.w;
        }
        #pragma unroll
        for (int m = 1; m <= 16; m <<= 1) { s += __shfl_xor(s, m); d += __shfl_xor(d, m); }
        if ((lane & 31) == 0) {
            int n2 = t*128 + tile*8 + w*2 + (lane >> 5);
            a_src[(size_t)(c*NN + n2)*HH + h] = s;
            a_dst[(size_t)(c*NN + n2)*HH + h] = d;
        }
    }

    // ---- coalesced copy stg -> Pg (8 nodes x 4 KB contiguous)
    {
        size_t gb = ((size_t)(c*NN) + t*128 + tile*8)*2048;
        const uint4* s4 = (const uint4*)stg;
        uint4* g4 = (uint4*)(Pg + gb);
        for (int l = tid; l < 2048; l += 256) g4[l] = s4[l];
    }
}

// ---------------------------------------------------------------------------
// K2: adjacency bitsets (dst-major and src-major)
// ---------------------------------------------------------------------------
__global__ __launch_bounds__(256) void k_adj(const int* __restrict__ ei,
                                             unsigned* __restrict__ adj,
                                             unsigned* __restrict__ adjT) {
    int e = blockIdx.x*256 + threadIdx.x;
    if (e >= EE) return;
    int s = ei[e];
    int d = ei[EE + e];
    int c = s >> 10;
    int i = s & 1023;
    int j = d & 1023;
    atomicOr(&adj [((size_t)((c << 10) + j))*32 + (i >> 5)], 1u << (i & 31));
    atomicOr(&adjT[((size_t)((c << 10) + i))*32 + (j >> 5)], 1u << (j & 31));
}

// ---------------------------------------------------------------------------
// K3: per-(c,j): list build + softmax stats (writes soff) + PV + head-mean
// grid = C*N, c = blockIdx&7 (XCD-pinned conformer), 256 threads (wave per h)
// ---------------------------------------------------------------------------
__global__ __launch_bounds__(256) void k5_attn(const unsigned short* __restrict__ Pg,
                                               const float* __restrict__ a_src,
                                               const float* __restrict__ a_dst,
                                               const unsigned* __restrict__ adj,
                                               float* __restrict__ soff,
                                               float* __restrict__ out) {
    __shared__ unsigned short L[128];
    __shared__ float attL[4][128];
    __shared__ int cnt;
    int bx = blockIdx.x;
    int c = bx & 7, j = bx >> 3;
    int cb = c << 10;
    int tid = threadIdx.x;
    if (tid == 0) cnt = 0;
    __syncthreads();

    const unsigned* aw = adj + (size_t)(cb + j)*32;
    #pragma unroll
    for (int rep = 0; rep < 4; ++rep) {
        int i = rep*256 + tid;
        if ((aw[i >> 5] >> (i & 31)) & 1u) {
            int pos = atomicAdd(&cnt, 1);
            if (pos < 128) L[pos] = (unsigned short)i;
        }
    }
    __syncthreads();
    int n = cnt; if (n > 128) n = 128;

    int h = tid >> 6, lane = tid & 63;
    float adv = a_dst[(size_t)(cb + j)*4 + h];

    float m = -1e30f;
    for (int e = lane; e < n; e += 64) {
        int i = L[e];
        float z = a_src[(size_t)(cb + i)*4 + h] + adv;
        z = (z < 0.f) ? 0.2f*z : z;          // leaky relu
        attL[h][e] = z;
        m = fmaxf(m, z);
    }
    #pragma unroll
    for (int mm = 32; mm; mm >>= 1) m = fmaxf(m, __shfl_xor(m, mm));
    float ssum = 0.f;
    for (int e = lane; e < n; e += 64) {
        float ez = __expf(attL[h][e] - m);
        attL[h][e] = ez;
        ssum += ez;
    }
    #pragma unroll
    for (int mm = 32; mm; mm >>= 1) ssum += __shfl_xor(ssum, mm);
    if (lane == 0) soff[(size_t)(cb + j)*4 + h] = m + __logf(ssum);
    float inv = 1.f / ssum;
    for (int e = lane; e < n; e += 64) attL[h][e] *= inv;
    __syncthreads();

    // PV: out[c,j,tf] = 0.25 * sum_h sum_e attL[h][e] * Pg[c][i][tf*4+h]
    #pragma unroll
    for (int rep = 0; rep < 2; ++rep) {
        int tf = rep*256 + tid;
        float acc = 0.f;
        for (int e = 0; e < n; ++e) {
            int i = L[e];
            uint2 pv = *(const uint2*)(Pg + ((size_t)(cb + i)*2048 + tf*4));
            acc += attL[0][e]*bf2f((unsigned short)(pv.x & 0xffffu))
                 + attL[1][e]*bf2f((unsigned short)(pv.x >> 16))
                 + attL[2][e]*bf2f((unsigned short)(pv.y & 0xffffu))
                 + attL[3][e]*bf2f((unsigned short)(pv.y >> 16));
        }
        out[(size_t)(cb + j)*512 + tf] = acc * 0.25f;
    }
}

// ---------------------------------------------------------------------------
// K4: dense attn writer — one block per (c,i) row, writes 16 KB coalesced
// attn[c][i][j][h] = edge ? exp(leaky(a_src+a_dst) - soff[c,j,h]) : 0
// ---------------------------------------------------------------------------
__global__ __launch_bounds__(256) void k4_attnw(const float* __restrict__ a_src,
                                                const float* __restrict__ a_dst,
                                                const float* __restrict__ soff,
                                                const unsigned* __restrict__ adjT,
                                                float* __restrict__ attn_out) {
    int bx = blockIdx.x;
    int c = bx & 7, i = bx >> 3;
    int cb = c << 10;
    int tid = threadIdx.x;
    const unsigned* aw = adjT + (size_t)(cb + i)*32;
    float as0 = a_src[(size_t)(cb + i)*4 + 0];
    float as1 = a_src[(size_t)(cb + i)*4 + 1];
    float as2 = a_src[(size_t)(cb + i)*4 + 2];
    float as3 = a_src[(size_t)(cb + i)*4 + 3];
    float* dst = attn_out + (size_t)(cb + i)*4096;
    #pragma unroll 4
    for (int it = 0; it < 16; ++it) {
        int jh = it*256 + tid;
        int j = jh >> 2, h = jh & 3;
        float val = 0.f;
        if ((aw[j >> 5] >> (j & 31)) & 1u) {
            float as = (h == 0) ? as0 : (h == 1) ? as1 : (h == 2) ? as2 : as3;
            float z = as + a_dst[(size_t)(cb + j)*4 + h];
            z = (z < 0.f) ? 0.2f*z : z;
            val = __expf(z - soff[(size_t)(cb + j)*4 + h]);
        }
        dst[jh] = val;
    }
}

// ---------------------------------------------------------------------------
extern "C" void kernel_launch(void* const* d_in, const int* in_sizes, int n_in,
                              void* d_out, int out_size, void* d_ws, size_t ws_size,
                              hipStream_t stream) {
    const int*   ei   = (const int*)d_in[0];
    const float* nf   = (const float*)d_in[1];
    const float* fc   = (const float*)d_in[2];
    const float* avs  = (const float*)d_in[3];
    const float* avd  = (const float*)d_in[4];

    float* out      = (float*)d_out;
    float* attn_out = out + OUT_ELEMS;

    char* ws = (char*)d_ws;
    unsigned short* Pg      = (unsigned short*)(ws + PG_OFF);
    float*          a_src_w = (float*)(ws + ASRC_OFF);
    float*          a_dst_w = (float*)(ws + ADST_OFF);
    float*          soff_w  = (float*)(ws + SOFF_OFF);
    unsigned*       adjw    = (unsigned*)(ws + ADJ_OFF);
    unsigned*       adjTw   = (unsigned*)(ws + ADJT_OFF);
    unsigned short* fcTw    = (unsigned short*)(ws + FCT_OFF);

    k0_prep <<<640, 256, 0, stream>>>(fc, fcTw, (uint4*)(ws + ADJ_OFF));
    k1_mfma <<<1024, 256, 0, stream>>>(nf, fcTw, avs, avd, Pg, a_src_w, a_dst_w);
    k_adj   <<<EE/256, 256, 0, stream>>>(ei, adjw, adjTw);
    k5_attn <<<CC*NN, 256, 0, stream>>>(Pg, a_src_w, a_dst_w, adjw, soff_w, out);
    k4_attnw<<<CC*NN, 256, 0, stream>>>(a_src_w, a_dst_w, soff_w, adjTw, attn_out);
}

// Round 5
// 102.741 us; speedup vs baseline: 1.7868x; 1.1570x over previous
//
#include <hip/hip_runtime.h>

typedef short  bf16x8 __attribute__((ext_vector_type(8)));
typedef float  f32x4  __attribute__((ext_vector_type(4)));

#define CC 8
#define NN 1024
#define TT 8
#define II 64
#define HH 4
#define FF 64
#define EE (CC*NN*16)          // 131072 edges
#define KK 256                 // F*H

static const size_t OUT_ELEMS  = (size_t)CC*NN*TT*FF;     // 4,194,304
static const size_t ATTN_ELEMS = (size_t)CC*NN*NN*HH;     // 33,554,432

// ws layout (bytes)
static const size_t PG_OFF   = 0;                          // Pg bf16 33,554,432
static const size_t ASRC_OFF = 33554432;                   // a_src f32 131,072
static const size_t ADST_OFF = ASRC_OFF + 131072;
static const size_t SOFF_OFF = ADST_OFF + 131072;
static const size_t ADJ_OFF  = SOFF_OFF + 131072;          // adj  1,048,576
static const size_t ADJT_OFF = ADJ_OFF + 1048576;          // adjT 1,048,576
static const size_t FCT_OFF  = ADJT_OFF + 1048576;         // fcT bf16 262,144

static __device__ inline unsigned short f2bf(float x) {
    union { float f; unsigned u; } q; q.f = x;
    unsigned r = q.u + 0x7fffu + ((q.u >> 16) & 1u);   // RNE
    return (unsigned short)(r >> 16);
}
static __device__ inline float bf2f(unsigned short u) {
    return __uint_as_float(((unsigned)u) << 16);
}

// ---------------------------------------------------------------------------
// K0: zero 2 MB adjacency region + transpose fc -> fcT[t][k][i] bf16
// ---------------------------------------------------------------------------
__global__ __launch_bounds__(256) void k0_prep(const float* __restrict__ fc,
                                               unsigned short* __restrict__ fcT,
                                               uint4* __restrict__ adjz) {
    int bx = blockIdx.x;
    int tid = threadIdx.x;
    if (bx < 512) {
        adjz[bx*256 + tid] = make_uint4(0u, 0u, 0u, 0u);
    } else {
        int gid = (bx - 512)*256 + tid;     // 32768 threads, 4 elems each
        int e0 = gid*4;                     // flat [t][k][i], i fastest
        int i0 = e0 & 63;
        int k  = (e0 >> 6) & 255;
        int t  = e0 >> 14;
        unsigned short v0 = f2bf(fc[(size_t)(t*64 + i0    )*KK + k]);
        unsigned short v1 = f2bf(fc[(size_t)(t*64 + i0 + 1)*KK + k]);
        unsigned short v2 = f2bf(fc[(size_t)(t*64 + i0 + 2)*KK + k]);
        unsigned short v3 = f2bf(fc[(size_t)(t*64 + i0 + 3)*KK + k]);
        uint2 pk;
        pk.x = (unsigned)v0 | ((unsigned)v1 << 16);
        pk.y = (unsigned)v2 | ((unsigned)v3 << 16);
        *(uint2*)&fcT[e0] = pk;
    }
}

// ---------------------------------------------------------------------------
// K1: MFMA projection + bf16 feat3-layout store + f32-precision logits
// grid = 8c * 8t * 16 rowtiles = 1024 blocks, 256 threads (4 waves)
// ---------------------------------------------------------------------------
__global__ __launch_bounds__(256) void k1_mfma(const float* __restrict__ nf,
                                               const unsigned short* __restrict__ fcT,
                                               const float* __restrict__ avs,
                                               const float* __restrict__ avd,
                                               unsigned short* __restrict__ Pg,
                                               float* __restrict__ a_src,
                                               float* __restrict__ a_dst) {
    __shared__ unsigned short stg[8*2048];     // 32 KB: 8 nodes x [t2][f2][h]
    __shared__ float avsL[2048];               // [h][ctl][col][t2]
    __shared__ float avdL[2048];
    int bx = blockIdx.x;
    int c = bx & 7, t = (bx >> 3) & 7, tile = bx >> 6;
    int tid = threadIdx.x;
    int w = tid >> 6, lane = tid & 63;
    int col = lane & 15, g = lane >> 4;

    for (int l = tid; l < 2048; l += 256) {
        int t2 = l & 7, cl = (l >> 3) & 15, ctl = (l >> 7) & 3, h = l >> 9;
        int si = h*512 + t2*64 + ctl*16 + cl;
        avsL[l] = avs[si];
        avdL[l] = avd[si];
    }

    int row = tile*64 + w*16 + col;
    const float* ap = nf + ((size_t)(c*NN + row)*TT + t)*II + g*8;
    bf16x8 afr[2];
    #pragma unroll
    for (int ks = 0; ks < 2; ++ks) {
        float4 x = *(const float4*)(ap + ks*32);
        float4 y = *(const float4*)(ap + ks*32 + 4);
        afr[ks][0] = (short)f2bf(x.x); afr[ks][1] = (short)f2bf(x.y);
        afr[ks][2] = (short)f2bf(x.z); afr[ks][3] = (short)f2bf(x.w);
        afr[ks][4] = (short)f2bf(y.x); afr[ks][5] = (short)f2bf(y.y);
        afr[ks][6] = (short)f2bf(y.z); afr[ks][7] = (short)f2bf(y.w);
    }

    const unsigned short* bp = fcT + (size_t)t*256*64 + col*64 + g*8;
    f32x4 acc[16];
    #pragma unroll
    for (int ct = 0; ct < 16; ++ct) {
        bf16x8 b0 = *(const bf16x8*)(bp + (size_t)ct*16*64);
        bf16x8 b1 = *(const bf16x8*)(bp + (size_t)ct*16*64 + 32);
        f32x4 a; a[0] = 0.f; a[1] = 0.f; a[2] = 0.f; a[3] = 0.f;
        a = __builtin_amdgcn_mfma_f32_16x16x32_bf16(afr[0], b0, a, 0, 0, 0);
        a = __builtin_amdgcn_mfma_f32_16x16x32_bf16(afr[1], b1, a, 0, 0, 0);
        acc[ct] = a;
    }

    int nd = w*2 + (g >> 1);
    int t2b = (g & 1)*4;
    #pragma unroll
    for (int ctl = 0; ctl < 4; ++ctl) {
        int f2 = ctl*16 + col;
        #pragma unroll
        for (int v = 0; v < 4; ++v) {
            unsigned u0 = (unsigned)f2bf(acc[ctl     ][v]) | ((unsigned)f2bf(acc[ 4+ctl][v]) << 16);
            unsigned u1 = (unsigned)f2bf(acc[ 8+ctl][v]) | ((unsigned)f2bf(acc[12+ctl][v]) << 16);
            *(uint2*)&stg[nd*2048 + (t2b + v)*256 + f2*4] = make_uint2(u0, u1);
        }
    }

    __syncthreads();

    #pragma unroll
    for (int h = 0; h < 4; ++h) {
        float s = 0.f, d = 0.f;
        #pragma unroll
        for (int ctl = 0; ctl < 4; ++ctl) {
            float4 wS = *(const float4*)&avsL[((h*4 + ctl)*16 + col)*8 + t2b];
            float4 wD = *(const float4*)&avdL[((h*4 + ctl)*16 + col)*8 + t2b];
            f32x4 a = acc[h*4 + ctl];
            s += a[0]*wS.x + a[1]*wS.y + a[2]*wS.z + a[3]*wS.w;
            d += a[0]*wD.x + a[1]*wD.y + a[2]*wD.z + a[3]*wD.w;
        }
        #pragma unroll
        for (int m = 1; m <= 16; m <<= 1) { s += __shfl_xor(s, m); d += __shfl_xor(d, m); }
        if ((lane & 31) == 0) {
            int n2 = t*128 + tile*8 + w*2 + (lane >> 5);
            a_src[(size_t)(c*NN + n2)*HH + h] = s;
            a_dst[(size_t)(c*NN + n2)*HH + h] = d;
        }
    }

    {
        size_t gb = ((size_t)(c*NN) + t*128 + tile*8)*2048;
        const uint4* s4 = (const uint4*)stg;
        uint4* g4 = (uint4*)(Pg + gb);
        for (int l = tid; l < 2048; l += 256) g4[l] = s4[l];
    }
}

// ---------------------------------------------------------------------------
// K2: adjacency bitsets (dst-major and src-major)
// ---------------------------------------------------------------------------
__global__ __launch_bounds__(256) void k_adj(const int* __restrict__ ei,
                                             unsigned* __restrict__ adj,
                                             unsigned* __restrict__ adjT) {
    int e = blockIdx.x*256 + threadIdx.x;
    if (e >= EE) return;
    int s = ei[e];
    int d = ei[EE + e];
    int c = s >> 10;
    int i = s & 1023;
    int j = d & 1023;
    atomicOr(&adj [((size_t)((c << 10) + j))*32 + (i >> 5)], 1u << (i & 31));
    atomicOr(&adjT[((size_t)((c << 10) + i))*32 + (j >> 5)], 1u << (j & 31));
}

// ---------------------------------------------------------------------------
// K3: per-(c,j): list build + softmax stats (writes soff) + PV + head-mean
// grid = C*N, c = blockIdx&7 (XCD-pinned conformer), 256 threads
// ---------------------------------------------------------------------------
__global__ __launch_bounds__(256) void k5_attn(const unsigned short* __restrict__ Pg,
                                               const float* __restrict__ a_src,
                                               const float* __restrict__ a_dst,
                                               const unsigned* __restrict__ adj,
                                               float* __restrict__ soff,
                                               float* __restrict__ out) {
    __shared__ unsigned short L[128];
    __shared__ float attL[4][128];
    __shared__ int cnt;
    int bx = blockIdx.x;
    int c = bx & 7, j = bx >> 3;
    int cb = c << 10;
    int tid = threadIdx.x;
    if (tid == 0) cnt = 0;
    __syncthreads();

    const unsigned* aw = adj + (size_t)(cb + j)*32;
    #pragma unroll
    for (int rep = 0; rep < 4; ++rep) {
        int i = rep*256 + tid;
        if ((aw[i >> 5] >> (i & 31)) & 1u) {
            int pos = atomicAdd(&cnt, 1);
            if (pos < 128) L[pos] = (unsigned short)i;
        }
    }
    __syncthreads();
    int n = cnt; if (n > 128) n = 128;

    int h = tid >> 6, lane = tid & 63;
    float adv = a_dst[(size_t)(cb + j)*4 + h];

    float m = -1e30f;
    for (int e = lane; e < n; e += 64) {
        int i = L[e];
        float z = a_src[(size_t)(cb + i)*4 + h] + adv;
        z = (z < 0.f) ? 0.2f*z : z;          // leaky relu
        attL[h][e] = z;
        m = fmaxf(m, z);
    }
    #pragma unroll
    for (int mm = 32; mm; mm >>= 1) m = fmaxf(m, __shfl_xor(m, mm));
    float ssum = 0.f;
    for (int e = lane; e < n; e += 64) {
        float ez = __expf(attL[h][e] - m);
        attL[h][e] = ez;
        ssum += ez;
    }
    #pragma unroll
    for (int mm = 32; mm; mm >>= 1) ssum += __shfl_xor(ssum, mm);
    if (lane == 0) soff[(size_t)(cb + j)*4 + h] = m + __logf(ssum);
    float inv = 1.f / ssum;
    for (int e = lane; e < n; e += 64) attL[h][e] *= inv;
    __syncthreads();

    // PV: thread tid owns tf pair {tid*2, tid*2+1}; uint4 (16B) gathers
    {
        float acc0 = 0.f, acc1 = 0.f;
        const unsigned short* pgBase = Pg + (size_t)cb*2048 + tid*8;
        for (int e = 0; e < n; ++e) {
            int i = L[e];
            uint4 pv = *(const uint4*)(pgBase + (size_t)i*2048);
            float w0 = attL[0][e], w1 = attL[1][e], w2 = attL[2][e], w3 = attL[3][e];
            acc0 += w0*bf2f((unsigned short)(pv.x & 0xffffu))
                  + w1*bf2f((unsigned short)(pv.x >> 16))
                  + w2*bf2f((unsigned short)(pv.y & 0xffffu))
                  + w3*bf2f((unsigned short)(pv.y >> 16));
            acc1 += w0*bf2f((unsigned short)(pv.z & 0xffffu))
                  + w1*bf2f((unsigned short)(pv.z >> 16))
                  + w2*bf2f((unsigned short)(pv.w & 0xffffu))
                  + w3*bf2f((unsigned short)(pv.w >> 16));
        }
        float2 o = make_float2(acc0 * 0.25f, acc1 * 0.25f);
        *(float2*)&out[(size_t)(cb + j)*512 + tid*2] = o;
    }
}

// ---------------------------------------------------------------------------
// K4: dense attn writer — one block per (c,i) row, float4 per (j)
// attn[c][i][j][h] = edge ? exp(leaky(a_src+a_dst) - soff[c,j,h]) : 0
// ---------------------------------------------------------------------------
__global__ __launch_bounds__(256) void k4_attnw(const float* __restrict__ a_src,
                                                const float* __restrict__ a_dst,
                                                const float* __restrict__ soff,
                                                const unsigned* __restrict__ adjT,
                                                float* __restrict__ attn_out) {
    int bx = blockIdx.x;
    int c = bx & 7, i = bx >> 3;
    int cb = c << 10;
    int tid = threadIdx.x;
    const unsigned* aw = adjT + (size_t)(cb + i)*32;
    float4 as4 = *(const float4*)&a_src[(size_t)(cb + i)*4];
    float4* dst = (float4*)(attn_out + (size_t)(cb + i)*4096);
    #pragma unroll
    for (int it = 0; it < 4; ++it) {
        int j = it*256 + tid;
        float4 val = make_float4(0.f, 0.f, 0.f, 0.f);
        if ((aw[j >> 5] >> (j & 31)) & 1u) {
            float4 ad = *(const float4*)&a_dst[(size_t)(cb + j)*4];
            float4 so = *(const float4*)&soff[(size_t)(cb + j)*4];
            float z0 = as4.x + ad.x; z0 = (z0 < 0.f) ? 0.2f*z0 : z0;
            float z1 = as4.y + ad.y; z1 = (z1 < 0.f) ? 0.2f*z1 : z1;
            float z2 = as4.z + ad.z; z2 = (z2 < 0.f) ? 0.2f*z2 : z2;
            float z3 = as4.w + ad.w; z3 = (z3 < 0.f) ? 0.2f*z3 : z3;
            val.x = __expf(z0 - so.x);
            val.y = __expf(z1 - so.y);
            val.z = __expf(z2 - so.z);
            val.w = __expf(z3 - so.w);
        }
        dst[j] = val;
    }
}

// ---------------------------------------------------------------------------
extern "C" void kernel_launch(void* const* d_in, const int* in_sizes, int n_in,
                              void* d_out, int out_size, void* d_ws, size_t ws_size,
                              hipStream_t stream) {
    const int*   ei   = (const int*)d_in[0];
    const float* nf   = (const float*)d_in[1];
    const float* fc   = (const float*)d_in[2];
    const float* avs  = (const float*)d_in[3];
    const float* avd  = (const float*)d_in[4];

    float* out      = (float*)d_out;
    float* attn_out = out + OUT_ELEMS;

    char* ws = (char*)d_ws;
    unsigned short* Pg      = (unsigned short*)(ws + PG_OFF);
    float*          a_src_w = (float*)(ws + ASRC_OFF);
    float*          a_dst_w = (float*)(ws + ADST_OFF);
    float*          soff_w  = (float*)(ws + SOFF_OFF);
    unsigned*       adjw    = (unsigned*)(ws + ADJ_OFF);
    unsigned*       adjTw   = (unsigned*)(ws + ADJT_OFF);
    unsigned short* fcTw    = (unsigned short*)(ws + FCT_OFF);

    k0_prep <<<640, 256, 0, stream>>>(fc, fcTw, (uint4*)(ws + ADJ_OFF));
    k1_mfma <<<1024, 256, 0, stream>>>(nf, fcTw, avs, avd, Pg, a_src_w, a_dst_w);
    k_adj   <<<EE/256, 256, 0, stream>>>(ei, adjw, adjTw);
    k5_attn <<<CC*NN, 256, 0, stream>>>(Pg, a_src_w, a_dst_w, adjw, soff_w, out);
    k4_attnw<<<CC*NN, 256, 0, stream>>>(a_src_w, a_dst_w, soff_w, adjTw, attn_out);
}

// Round 6
// 94.485 us; speedup vs baseline: 1.9430x; 1.0874x over previous
//
#include <hip/hip_runtime.h>

typedef short  bf16x8 __attribute__((ext_vector_type(8)));
typedef float  f32x4  __attribute__((ext_vector_type(4)));

#define CC 8
#define NN 1024
#define TT 8
#define II 64
#define HH 4
#define FF 64
#define EE (CC*NN*16)          // 131072 edges
#define KK 256                 // F*H

static const size_t OUT_ELEMS  = (size_t)CC*NN*TT*FF;     // 4,194,304
static const size_t ATTN_ELEMS = (size_t)CC*NN*NN*HH;     // 33,554,432

// ws layout (bytes)
static const size_t PG_OFF   = 0;                          // Pg bf16 33,554,432
static const size_t ASRC_OFF = 33554432;                   // a_src f32 131,072
static const size_t ADST_OFF = ASRC_OFF + 131072;
static const size_t ADJ_OFF  = ADST_OFF + 131072;          // adj  1,048,576
static const size_t FCT_OFF  = ADJ_OFF + 1048576;          // fcT bf16 262,144

static __device__ inline unsigned short f2bf(float x) {
    union { float f; unsigned u; } q; q.f = x;
    unsigned r = q.u + 0x7fffu + ((q.u >> 16) & 1u);   // RNE
    return (unsigned short)(r >> 16);
}
static __device__ inline float bf2f(unsigned short u) {
    return __uint_as_float(((unsigned)u) << 16);
}

// ---------------------------------------------------------------------------
// K0: zero 1 MB adj bitset (128 blocks) + coalesced fc->fcT[t][k][i] bf16
// transpose via LDS (32 blocks: one per (t, 16-wide i-block))
// ---------------------------------------------------------------------------
__global__ __launch_bounds__(256) void k0_prep(const float* __restrict__ fc,
                                               unsigned short* __restrict__ fcT,
                                               uint4* __restrict__ adjz) {
    int bx = blockIdx.x;
    int tid = threadIdx.x;
    if (bx < 64) {                       // 64 blocks x 16 KB = 1 MB
        uint4 z = make_uint4(0u, 0u, 0u, 0u);
        uint4* p = adjz + (size_t)bx*1024;
        #pragma unroll
        for (int r = 0; r < 4; ++r) p[r*256 + tid] = z;
    } else {
        int b = bx - 64;                 // 0..31
        int t = b >> 2, ib = (b & 3) << 4;
        __shared__ unsigned short ls[256][17];   // [k][i'] pad 17
        #pragma unroll
        for (int r = 0; r < 16; ++r)
            ls[tid][r] = f2bf(fc[(size_t)(t*64 + ib + r)*KK + tid]);  // coalesced
        __syncthreads();
        int ii = tid & 15, k0 = tid >> 4;
        #pragma unroll
        for (int it = 0; it < 16; ++it) {
            int k = it*16 + k0;
            fcT[(size_t)t*16384 + (size_t)k*64 + ib + ii] = ls[k][ii];
        }
    }
}

// ---------------------------------------------------------------------------
// K1 (fused): blocks [0,1024) MFMA projection + logits; [1024,1536) adjacency
// bitset build; [1536, 9728) zero-fill of dense attn output (overlaps!)
// ---------------------------------------------------------------------------
__global__ __launch_bounds__(256) void k1_mfma(const float* __restrict__ nf,
                                               const unsigned short* __restrict__ fcT,
                                               const float* __restrict__ avs,
                                               const float* __restrict__ avd,
                                               unsigned short* __restrict__ Pg,
                                               float* __restrict__ a_src,
                                               float* __restrict__ a_dst,
                                               const int* __restrict__ ei,
                                               unsigned* __restrict__ adj,
                                               uint4* __restrict__ attnz) {
    int bxg = blockIdx.x;
    int tid = threadIdx.x;

    if (bxg >= 1536) {                   // ---- attn zero-fill: 8192 blocks x 16 KB
        uint4 z = make_uint4(0u, 0u, 0u, 0u);
        uint4* p = attnz + (size_t)(bxg - 1536)*1024;
        #pragma unroll
        for (int r = 0; r < 4; ++r) p[r*256 + tid] = z;
        return;
    }
    if (bxg >= 1024) {                   // ---- adjacency bitset: 512 blocks
        int e = (bxg - 1024)*256 + tid;
        int s = ei[e];
        int d = ei[EE + e];
        int c = s >> 10, i = s & 1023, j = d & 1023;
        atomicOr(&adj[((size_t)((c << 10) + j))*32 + (i >> 5)], 1u << (i & 31));
        return;
    }

    // ---- MFMA projection (blocks 0..1023)
    __shared__ unsigned short stg[8*2048];     // 32 KB: 8 nodes x [t2][f2][h]
    __shared__ float avsL[2048];               // [h][ctl][col][t2]
    __shared__ float avdL[2048];
    int bx = bxg;
    int c = bx & 7, t = (bx >> 3) & 7, tile = bx >> 6;
    int w = tid >> 6, lane = tid & 63;
    int col = lane & 15, g = lane >> 4;

    for (int l = tid; l < 2048; l += 256) {
        int t2 = l & 7, cl = (l >> 3) & 15, ctl = (l >> 7) & 3, h = l >> 9;
        int si = h*512 + t2*64 + ctl*16 + cl;
        avsL[l] = avs[si];
        avdL[l] = avd[si];
    }

    int row = tile*64 + w*16 + col;
    const float* ap = nf + ((size_t)(c*NN + row)*TT + t)*II + g*8;
    bf16x8 afr[2];
    #pragma unroll
    for (int ks = 0; ks < 2; ++ks) {
        float4 x = *(const float4*)(ap + ks*32);
        float4 y = *(const float4*)(ap + ks*32 + 4);
        afr[ks][0] = (short)f2bf(x.x); afr[ks][1] = (short)f2bf(x.y);
        afr[ks][2] = (short)f2bf(x.z); afr[ks][3] = (short)f2bf(x.w);
        afr[ks][4] = (short)f2bf(y.x); afr[ks][5] = (short)f2bf(y.y);
        afr[ks][6] = (short)f2bf(y.z); afr[ks][7] = (short)f2bf(y.w);
    }

    const unsigned short* bp = fcT + (size_t)t*256*64 + col*64 + g*8;
    f32x4 acc[16];
    #pragma unroll
    for (int ct = 0; ct < 16; ++ct) {
        bf16x8 b0 = *(const bf16x8*)(bp + (size_t)ct*16*64);
        bf16x8 b1 = *(const bf16x8*)(bp + (size_t)ct*16*64 + 32);
        f32x4 a; a[0] = 0.f; a[1] = 0.f; a[2] = 0.f; a[3] = 0.f;
        a = __builtin_amdgcn_mfma_f32_16x16x32_bf16(afr[0], b0, a, 0, 0, 0);
        a = __builtin_amdgcn_mfma_f32_16x16x32_bf16(afr[1], b1, a, 0, 0, 0);
        acc[ct] = a;
    }

    int nd = w*2 + (g >> 1);
    int t2b = (g & 1)*4;
    #pragma unroll
    for (int ctl = 0; ctl < 4; ++ctl) {
        int f2 = ctl*16 + col;
        #pragma unroll
        for (int v = 0; v < 4; ++v) {
            unsigned u0 = (unsigned)f2bf(acc[ctl     ][v]) | ((unsigned)f2bf(acc[ 4+ctl][v]) << 16);
            unsigned u1 = (unsigned)f2bf(acc[ 8+ctl][v]) | ((unsigned)f2bf(acc[12+ctl][v]) << 16);
            *(uint2*)&stg[nd*2048 + (t2b + v)*256 + f2*4] = make_uint2(u0, u1);
        }
    }

    __syncthreads();

    #pragma unroll
    for (int h = 0; h < 4; ++h) {
        float s = 0.f, d = 0.f;
        #pragma unroll
        for (int ctl = 0; ctl < 4; ++ctl) {
            float4 wS = *(const float4*)&avsL[((h*4 + ctl)*16 + col)*8 + t2b];
            float4 wD = *(const float4*)&avdL[((h*4 + ctl)*16 + col)*8 + t2b];
            f32x4 a = acc[h*4 + ctl];
            s += a[0]*wS.x + a[1]*wS.y + a[2]*wS.z + a[3]*wS.w;
            d += a[0]*wD.x + a[1]*wD.y + a[2]*wD.z + a[3]*wD.w;
        }
        #pragma unroll
        for (int m = 1; m <= 16; m <<= 1) { s += __shfl_xor(s, m); d += __shfl_xor(d, m); }
        if ((lane & 31) == 0) {
            int n2 = t*128 + tile*8 + w*2 + (lane >> 5);
            a_src[(size_t)(c*NN + n2)*HH + h] = s;
            a_dst[(size_t)(c*NN + n2)*HH + h] = d;
        }
    }

    {
        size_t gb = ((size_t)(c*NN) + t*128 + tile*8)*2048;
        const uint4* s4 = (const uint4*)stg;
        uint4* g4 = (uint4*)(Pg + gb);
        for (int l = tid; l < 2048; l += 256) g4[l] = s4[l];
    }
}

// ---------------------------------------------------------------------------
// K5: per-(c,j): list build + softmax + attn float4 scatter + PV + head-mean
// grid = C*N, c = blockIdx&7 (XCD-pinned conformer), 256 threads
// ---------------------------------------------------------------------------
__global__ __launch_bounds__(256) void k5_attn(const unsigned short* __restrict__ Pg,
                                               const float* __restrict__ a_src,
                                               const float* __restrict__ a_dst,
                                               const unsigned* __restrict__ adj,
                                               float* __restrict__ attn_out,
                                               float* __restrict__ out) {
    __shared__ unsigned short L[128];
    __shared__ float attL[128][4];     // [e][h]
    __shared__ int cnt;
    int bx = blockIdx.x;
    int c = bx & 7, j = bx >> 3;
    int cb = c << 10;
    int tid = threadIdx.x;
    if (tid == 0) cnt = 0;
    __syncthreads();

    const unsigned* aw = adj + (size_t)(cb + j)*32;
    #pragma unroll
    for (int rep = 0; rep < 4; ++rep) {
        int i = rep*256 + tid;
        if ((aw[i >> 5] >> (i & 31)) & 1u) {
            int pos = atomicAdd(&cnt, 1);
            if (pos < 128) L[pos] = (unsigned short)i;
        }
    }
    __syncthreads();
    int n = cnt; if (n > 128) n = 128;

    int h = tid >> 6, lane = tid & 63;
    float adv = a_dst[(size_t)(cb + j)*4 + h];

    float m = -1e30f;
    for (int e = lane; e < n; e += 64) {
        float z = a_src[(size_t)(cb + L[e])*4 + h] + adv;
        z = (z < 0.f) ? 0.2f*z : z;          // leaky relu
        attL[e][h] = z;
        m = fmaxf(m, z);
    }
    #pragma unroll
    for (int mm = 32; mm; mm >>= 1) m = fmaxf(m, __shfl_xor(m, mm));
    float ssum = 0.f;
    for (int e = lane; e < n; e += 64) {
        float ez = __expf(attL[e][h] - m);
        attL[e][h] = ez;
        ssum += ez;
    }
    #pragma unroll
    for (int mm = 32; mm; mm >>= 1) ssum += __shfl_xor(ssum, mm);
    float inv = 1.f / ssum;
    for (int e = lane; e < n; e += 64) attL[e][h] *= inv;
    __syncthreads();

    // scatter the nonzero attn entries (normalized probs) as float4 per edge
    if (tid < n) {
        int i = L[tid];
        *(float4*)&attn_out[((size_t)(cb + i)*NN + j)*4] = *(const float4*)attL[tid];
    }

    // PV with 1-deep prefetch: thread owns tf pair {tid*2, tid*2+1}
    float acc0 = 0.f, acc1 = 0.f;
    const unsigned short* pgBase = Pg + (size_t)cb*2048 + tid*8;
    if (n > 0) {
        uint4  pv = *(const uint4*)(pgBase + (size_t)L[0]*2048);
        float4 wv = *(const float4*)attL[0];
        for (int e = 0; e < n; ++e) {
            uint4  nx = pv; float4 wn = wv;
            if (e + 1 < n) {
                nx = *(const uint4*)(pgBase + (size_t)L[e+1]*2048);
                wn = *(const float4*)attL[e+1];
            }
            acc0 += wv.x*bf2f((unsigned short)(pv.x & 0xffffu))
                  + wv.y*bf2f((unsigned short)(pv.x >> 16))
                  + wv.z*bf2f((unsigned short)(pv.y & 0xffffu))
                  + wv.w*bf2f((unsigned short)(pv.y >> 16));
            acc1 += wv.x*bf2f((unsigned short)(pv.z & 0xffffu))
                  + wv.y*bf2f((unsigned short)(pv.z >> 16))
                  + wv.z*bf2f((unsigned short)(pv.w & 0xffffu))
                  + wv.w*bf2f((unsigned short)(pv.w >> 16));
            pv = nx; wv = wn;
        }
    }
    *(float2*)&out[(size_t)(cb + j)*512 + tid*2] = make_float2(acc0*0.25f, acc1*0.25f);
}

// ---------------------------------------------------------------------------
extern "C" void kernel_launch(void* const* d_in, const int* in_sizes, int n_in,
                              void* d_out, int out_size, void* d_ws, size_t ws_size,
                              hipStream_t stream) {
    const int*   ei   = (const int*)d_in[0];
    const float* nf   = (const float*)d_in[1];
    const float* fc   = (const float*)d_in[2];
    const float* avs  = (const float*)d_in[3];
    const float* avd  = (const float*)d_in[4];

    float* out      = (float*)d_out;
    float* attn_out = out + OUT_ELEMS;

    char* ws = (char*)d_ws;
    unsigned short* Pg      = (unsigned short*)(ws + PG_OFF);
    float*          a_src_w = (float*)(ws + ASRC_OFF);
    float*          a_dst_w = (float*)(ws + ADST_OFF);
    unsigned*       adjw    = (unsigned*)(ws + ADJ_OFF);
    unsigned short* fcTw    = (unsigned short*)(ws + FCT_OFF);

    k0_prep <<<96, 256, 0, stream>>>(fc, fcTw, (uint4*)(ws + ADJ_OFF));
    k1_mfma <<<9728, 256, 0, stream>>>(nf, fcTw, avs, avd, Pg, a_src_w, a_dst_w,
                                       ei, adjw, (uint4*)attn_out);
    k5_attn <<<CC*NN, 256, 0, stream>>>(Pg, a_src_w, a_dst_w, adjw, attn_out, out);
}

// Round 7
// 90.263 us; speedup vs baseline: 2.0338x; 1.0468x over previous
//
#include <hip/hip_runtime.h>

typedef short  bf16x8 __attribute__((ext_vector_type(8)));
typedef float  f32x4  __attribute__((ext_vector_type(4)));
typedef float  f32x2  __attribute__((ext_vector_type(2)));
typedef unsigned u32x4 __attribute__((ext_vector_type(4)));

#define CC 8
#define NN 1024
#define TT 8
#define II 64
#define HH 4
#define FF 64
#define EE (CC*NN*16)          // 131072 edges
#define KK 256                 // F*H

static const size_t OUT_ELEMS  = (size_t)CC*NN*TT*FF;     // 4,194,304
static const size_t ATTN_ELEMS = (size_t)CC*NN*NN*HH;     // 33,554,432

// ws layout (bytes)
static const size_t PG_OFF   = 0;                          // Pg bf16 33,554,432
static const size_t ASRC_OFF = 33554432;                   // a_src f32 131,072
static const size_t ADST_OFF = ASRC_OFF + 131072;
static const size_t ADJ_OFF  = ADST_OFF + 131072;          // adj  1,048,576
static const size_t FCT_OFF  = ADJ_OFF + 1048576;          // fcT bf16 262,144

static __device__ inline unsigned short f2bf(float x) {
    union { float f; unsigned u; } q; q.f = x;
    unsigned r = q.u + 0x7fffu + ((q.u >> 16) & 1u);   // RNE
    return (unsigned short)(r >> 16);
}
static __device__ inline float bf2f(unsigned short u) {
    return __uint_as_float(((unsigned)u) << 16);
}

// ---------------------------------------------------------------------------
// K0: zero 1 MB adj bitset + coalesced fc->fcT[t][k][i] bf16 transpose
// ---------------------------------------------------------------------------
__global__ __launch_bounds__(256) void k0_prep(const float* __restrict__ fc,
                                               unsigned short* __restrict__ fcT,
                                               uint4* __restrict__ adjz) {
    int bx = blockIdx.x;
    int tid = threadIdx.x;
    if (bx < 64) {                       // 64 blocks x 16 KB = 1 MB
        uint4 z = make_uint4(0u, 0u, 0u, 0u);
        uint4* p = adjz + (size_t)bx*1024;
        #pragma unroll
        for (int r = 0; r < 4; ++r) p[r*256 + tid] = z;
    } else {
        int b = bx - 64;                 // 0..31
        int t = b >> 2, ib = (b & 3) << 4;
        __shared__ unsigned short ls[256][17];   // [k][i'] pad 17
        #pragma unroll
        for (int r = 0; r < 16; ++r)
            ls[tid][r] = f2bf(fc[(size_t)(t*64 + ib + r)*KK + tid]);  // coalesced
        __syncthreads();
        int ii = tid & 15, k0 = tid >> 4;
        #pragma unroll
        for (int it = 0; it < 16; ++it) {
            int k = it*16 + k0;
            fcT[(size_t)t*16384 + (size_t)k*64 + ib + ii] = ls[k][ii];
        }
    }
}

// ---------------------------------------------------------------------------
// K1 (fused): blocks [0,1024) MFMA projection + logits; [1024,1536) adjacency
// bitset; [1536, 9728) NONTEMPORAL zero-fill of dense attn (no L2 pollution)
// ---------------------------------------------------------------------------
__global__ __launch_bounds__(256) void k1_mfma(const float* __restrict__ nf,
                                               const unsigned short* __restrict__ fcT,
                                               const float* __restrict__ avs,
                                               const float* __restrict__ avd,
                                               unsigned short* __restrict__ Pg,
                                               float* __restrict__ a_src,
                                               float* __restrict__ a_dst,
                                               const int* __restrict__ ei,
                                               unsigned* __restrict__ adj,
                                               u32x4* __restrict__ attnz) {
    int bxg = blockIdx.x;
    int tid = threadIdx.x;

    if (bxg >= 1536) {                   // ---- attn zero-fill: 8192 blocks x 16 KB
        u32x4 z = (u32x4)(0u);
        u32x4* p = attnz + (size_t)(bxg - 1536)*1024;
        #pragma unroll
        for (int r = 0; r < 4; ++r)
            __builtin_nontemporal_store(z, &p[r*256 + tid]);
        return;
    }
    if (bxg >= 1024) {                   // ---- adjacency bitset: 512 blocks
        int e = (bxg - 1024)*256 + tid;
        int s = ei[e];
        int d = ei[EE + e];
        int c = s >> 10, i = s & 1023, j = d & 1023;
        atomicOr(&adj[((size_t)((c << 10) + j))*32 + (i >> 5)], 1u << (i & 31));
        return;
    }

    // ---- MFMA projection (blocks 0..1023)
    __shared__ unsigned short stg[8*2048];     // 32 KB: 8 nodes x [t2][f2][h]
    __shared__ float avsL[2048];               // [h][ctl][col][t2]
    __shared__ float avdL[2048];
    int bx = bxg;
    int c = bx & 7, t = (bx >> 3) & 7, tile = bx >> 6;
    int w = tid >> 6, lane = tid & 63;
    int col = lane & 15, g = lane >> 4;

    for (int l = tid; l < 2048; l += 256) {
        int t2 = l & 7, cl = (l >> 3) & 15, ctl = (l >> 7) & 3, h = l >> 9;
        int si = h*512 + t2*64 + ctl*16 + cl;
        avsL[l] = avs[si];
        avdL[l] = avd[si];
    }

    int row = tile*64 + w*16 + col;
    const float* ap = nf + ((size_t)(c*NN + row)*TT + t)*II + g*8;
    bf16x8 afr[2];
    #pragma unroll
    for (int ks = 0; ks < 2; ++ks) {
        float4 x = *(const float4*)(ap + ks*32);
        float4 y = *(const float4*)(ap + ks*32 + 4);
        afr[ks][0] = (short)f2bf(x.x); afr[ks][1] = (short)f2bf(x.y);
        afr[ks][2] = (short)f2bf(x.z); afr[ks][3] = (short)f2bf(x.w);
        afr[ks][4] = (short)f2bf(y.x); afr[ks][5] = (short)f2bf(y.y);
        afr[ks][6] = (short)f2bf(y.z); afr[ks][7] = (short)f2bf(y.w);
    }

    const unsigned short* bp = fcT + (size_t)t*256*64 + col*64 + g*8;
    f32x4 acc[16];
    #pragma unroll
    for (int ct = 0; ct < 16; ++ct) {
        bf16x8 b0 = *(const bf16x8*)(bp + (size_t)ct*16*64);
        bf16x8 b1 = *(const bf16x8*)(bp + (size_t)ct*16*64 + 32);
        f32x4 a; a[0] = 0.f; a[1] = 0.f; a[2] = 0.f; a[3] = 0.f;
        a = __builtin_amdgcn_mfma_f32_16x16x32_bf16(afr[0], b0, a, 0, 0, 0);
        a = __builtin_amdgcn_mfma_f32_16x16x32_bf16(afr[1], b1, a, 0, 0, 0);
        acc[ct] = a;
    }

    int nd = w*2 + (g >> 1);
    int t2b = (g & 1)*4;
    #pragma unroll
    for (int ctl = 0; ctl < 4; ++ctl) {
        int f2 = ctl*16 + col;
        #pragma unroll
        for (int v = 0; v < 4; ++v) {
            unsigned u0 = (unsigned)f2bf(acc[ctl     ][v]) | ((unsigned)f2bf(acc[ 4+ctl][v]) << 16);
            unsigned u1 = (unsigned)f2bf(acc[ 8+ctl][v]) | ((unsigned)f2bf(acc[12+ctl][v]) << 16);
            *(uint2*)&stg[nd*2048 + (t2b + v)*256 + f2*4] = make_uint2(u0, u1);
        }
    }

    __syncthreads();

    #pragma unroll
    for (int h = 0; h < 4; ++h) {
        float s = 0.f, d = 0.f;
        #pragma unroll
        for (int ctl = 0; ctl < 4; ++ctl) {
            float4 wS = *(const float4*)&avsL[((h*4 + ctl)*16 + col)*8 + t2b];
            float4 wD = *(const float4*)&avdL[((h*4 + ctl)*16 + col)*8 + t2b];
            f32x4 a = acc[h*4 + ctl];
            s += a[0]*wS.x + a[1]*wS.y + a[2]*wS.z + a[3]*wS.w;
            d += a[0]*wD.x + a[1]*wD.y + a[2]*wD.z + a[3]*wD.w;
        }
        #pragma unroll
        for (int m = 1; m <= 16; m <<= 1) { s += __shfl_xor(s, m); d += __shfl_xor(d, m); }
        if ((lane & 31) == 0) {
            int n2 = t*128 + tile*8 + w*2 + (lane >> 5);
            a_src[(size_t)(c*NN + n2)*HH + h] = s;
            a_dst[(size_t)(c*NN + n2)*HH + h] = d;
        }
    }

    {
        size_t gb = ((size_t)(c*NN) + t*128 + tile*8)*2048;
        const uint4* s4 = (const uint4*)stg;
        uint4* g4 = (uint4*)(Pg + gb);
        for (int l = tid; l < 2048; l += 256) g4[l] = s4[l];
    }
}

static __device__ inline void fma8(uint4 pv, float4 wv, float& a0, float& a1) {
    a0 += wv.x*bf2f((unsigned short)(pv.x & 0xffffu))
        + wv.y*bf2f((unsigned short)(pv.x >> 16))
        + wv.z*bf2f((unsigned short)(pv.y & 0xffffu))
        + wv.w*bf2f((unsigned short)(pv.y >> 16));
    a1 += wv.x*bf2f((unsigned short)(pv.z & 0xffffu))
        + wv.y*bf2f((unsigned short)(pv.z >> 16))
        + wv.z*bf2f((unsigned short)(pv.w & 0xffffu))
        + wv.w*bf2f((unsigned short)(pv.w >> 16));
}

// ---------------------------------------------------------------------------
// K5: per-(c,j): list build + softmax + attn nt-scatter + PV (4-deep) + mean
// grid = C*N, c = blockIdx&7 (XCD-pinned conformer), 256 threads
// ---------------------------------------------------------------------------
__global__ __launch_bounds__(256) void k5_attn(const unsigned short* __restrict__ Pg,
                                               const float* __restrict__ a_src,
                                               const float* __restrict__ a_dst,
                                               const unsigned* __restrict__ adj,
                                               float* __restrict__ attn_out,
                                               float* __restrict__ out) {
    __shared__ unsigned short L[128];
    __shared__ __align__(16) float attL[128][4];     // [e][h]
    __shared__ int cnt;
    int bx = blockIdx.x;
    int c = bx & 7, j = bx >> 3;
    int cb = c << 10;
    int tid = threadIdx.x;
    if (tid == 0) cnt = 0;
    __syncthreads();

    const unsigned* aw = adj + (size_t)(cb + j)*32;
    #pragma unroll
    for (int rep = 0; rep < 4; ++rep) {
        int i = rep*256 + tid;
        if ((aw[i >> 5] >> (i & 31)) & 1u) {
            int pos = atomicAdd(&cnt, 1);
            if (pos < 128) L[pos] = (unsigned short)i;
        }
    }
    __syncthreads();
    int n = cnt; if (n > 128) n = 128;
    int nn = (n + 3) & ~3;

    // pad list to multiple of 4 with zero-weight entries (enables 4-deep PV)
    if (tid >= n && tid < nn) {
        L[tid] = (unsigned short)(n ? L[0] : 0);
        *(f32x4*)attL[tid] = (f32x4)(0.f);
    }

    int h = tid >> 6, lane = tid & 63;
    float adv = a_dst[(size_t)(cb + j)*4 + h];

    float m = -1e30f;
    for (int e = lane; e < n; e += 64) {
        float z = a_src[(size_t)(cb + L[e])*4 + h] + adv;
        z = (z < 0.f) ? 0.2f*z : z;          // leaky relu
        attL[e][h] = z;
        m = fmaxf(m, z);
    }
    #pragma unroll
    for (int mm = 32; mm; mm >>= 1) m = fmaxf(m, __shfl_xor(m, mm));
    float ssum = 0.f;
    for (int e = lane; e < n; e += 64) {
        float ez = __expf(attL[e][h] - m);
        attL[e][h] = ez;
        ssum += ez;
    }
    #pragma unroll
    for (int mm = 32; mm; mm >>= 1) ssum += __shfl_xor(ssum, mm);
    float inv = 1.f / ssum;
    for (int e = lane; e < n; e += 64) attL[e][h] *= inv;
    __syncthreads();

    // nt-scatter nonzero attn entries (bypass L2 — keep Pg resident)
    if (tid < n) {
        int i = L[tid];
        f32x4 sv = *(const f32x4*)attL[tid];
        __builtin_nontemporal_store(sv, (f32x4*)&attn_out[((size_t)(cb + i)*NN + j)*4]);
    }

    // PV, 4 independent row-loads in flight; thread owns tf pair {2tid, 2tid+1}
    float acc0 = 0.f, acc1 = 0.f, acc2 = 0.f, acc3 = 0.f;
    const unsigned short* pgBase = Pg + (size_t)cb*2048 + tid*8;
    for (int e0 = 0; e0 < nn; e0 += 4) {
        uint4 p0 = *(const uint4*)(pgBase + (size_t)L[e0+0]*2048);
        uint4 p1 = *(const uint4*)(pgBase + (size_t)L[e0+1]*2048);
        uint4 p2 = *(const uint4*)(pgBase + (size_t)L[e0+2]*2048);
        uint4 p3 = *(const uint4*)(pgBase + (size_t)L[e0+3]*2048);
        float4 w0 = *(const float4*)attL[e0+0];
        float4 w1 = *(const float4*)attL[e0+1];
        float4 w2 = *(const float4*)attL[e0+2];
        float4 w3 = *(const float4*)attL[e0+3];
        fma8(p0, w0, acc0, acc1);
        fma8(p1, w1, acc2, acc3);
        fma8(p2, w2, acc0, acc1);
        fma8(p3, w3, acc2, acc3);
    }
    f32x2 o;
    o[0] = (acc0 + acc2) * 0.25f;
    o[1] = (acc1 + acc3) * 0.25f;
    __builtin_nontemporal_store(o, (f32x2*)&out[(size_t)(cb + j)*512 + tid*2]);
}

// ---------------------------------------------------------------------------
extern "C" void kernel_launch(void* const* d_in, const int* in_sizes, int n_in,
                              void* d_out, int out_size, void* d_ws, size_t ws_size,
                              hipStream_t stream) {
    const int*   ei   = (const int*)d_in[0];
    const float* nf   = (const float*)d_in[1];
    const float* fc   = (const float*)d_in[2];
    const float* avs  = (const float*)d_in[3];
    const float* avd  = (const float*)d_in[4];

    float* out      = (float*)d_out;
    float* attn_out = out + OUT_ELEMS;

    char* ws = (char*)d_ws;
    unsigned short* Pg      = (unsigned short*)(ws + PG_OFF);
    float*          a_src_w = (float*)(ws + ASRC_OFF);
    float*          a_dst_w = (float*)(ws + ADST_OFF);
    unsigned*       adjw    = (unsigned*)(ws + ADJ_OFF);
    unsigned short* fcTw    = (unsigned short*)(ws + FCT_OFF);

    k0_prep <<<96, 256, 0, stream>>>(fc, fcTw, (uint4*)(ws + ADJ_OFF));
    k1_mfma <<<9728, 256, 0, stream>>>(nf, fcTw, avs, avd, Pg, a_src_w, a_dst_w,
                                       ei, adjw, (u32x4*)attn_out);
    k5_attn <<<CC*NN, 256, 0, stream>>>(Pg, a_src_w, a_dst_w, adjw, attn_out, out);
}